// Round 1
// baseline (803.805 us; speedup 1.0000x reference)
//
#include <hip/hip_runtime.h>
#include <math.h>

#define S_LEN  1024
#define EMB    2048
#define NH_    8
#define DH_    256
#define TOKENS 2048   // B*S
#define NBH    16     // B*NH

typedef __attribute__((ext_vector_type(4))) float    f32x4;
typedef __attribute__((ext_vector_type(8))) _Float16 f16x8;
typedef __attribute__((ext_vector_type(4))) _Float16 f16x4;

__device__ __forceinline__ _Float16 f2h(float f) { return (_Float16)f; }

// ---------------------------------------------------------------------------
// Generic tiled MFMA GEMM: C[M,N] = A[M,K] @ B[K,N]  (A f32 or f16, B f32, C f32)
// Block 256 thr = 4 waves (2x2), tile 128x128, BK=32, f16 16x16x32 MFMA.
// LDS tiles padded to stride 40 (80 B) -> frag ds_read_b128 ~conflict-free.
// causal!=0: K-loop limited to m0+128 (used for h = W @ V with lower-tri W).
// B batch pointer advances every zdivB z-slices (v shared across 8 heads).
// ---------------------------------------------------------------------------
template<bool A_IS_F16>
__global__ __launch_bounds__(256) void gemm_kernel(
    const void* __restrict__ Ag, const float* __restrict__ Bg,
    float* __restrict__ Cg, int K, int lda, int ldb, int ldc,
    long sA, long sB, long sC, int zdivB, int causal)
{
  __shared__ _Float16 As[128][40];
  __shared__ _Float16 Bs[128][40];
  const int tid = threadIdx.x;
  const int n0 = blockIdx.x * 128;
  const int m0 = blockIdx.y * 128;
  const int z  = blockIdx.z;
  const float* Bp = Bg + (long)(z / zdivB) * sB + n0;
  float* Cp = Cg + (long)z * sC;
  const int lane = tid & 63, wid = tid >> 6;
  const int wr = wid >> 1, wc = wid & 1;
  const int lrow = lane & 15, kseg = lane >> 4;
  const int kl = causal ? ((m0 + 128 < K) ? (m0 + 128) : K) : K;

  f32x4 acc[4][4] = {};
  for (int k0 = 0; k0 < kl; k0 += 32) {
    if (!A_IS_F16) {
      const float* Ap = (const float*)Ag + (long)z * sA + (long)m0 * lda + k0;
      #pragma unroll
      for (int i = 0; i < 4; ++i) {
        const int t4 = tid + i * 256;
        const int row = t4 >> 3, c4 = t4 & 7;      // 8 float4 per 32-wide row
        const float4 f = *(const float4*)(Ap + (long)row * lda + c4 * 4);
        f16x4 h4 = {f2h(f.x), f2h(f.y), f2h(f.z), f2h(f.w)};
        *(f16x4*)&As[row][c4 * 4] = h4;
      }
    } else {
      const _Float16* Ap = (const _Float16*)Ag + (long)z * sA + (long)m0 * lda + k0;
      #pragma unroll
      for (int i = 0; i < 2; ++i) {
        const int t8 = tid + i * 256;
        const int row = t8 >> 2, c8 = t8 & 3;      // 4 f16x8 per 32-wide row
        *(f16x8*)&As[row][c8 * 8] = *(const f16x8*)(Ap + (long)row * lda + c8 * 8);
      }
    }
    { // B tile: rows k0..k0+31, cols n0..n0+127, store transposed [n][k]
      const float* Bq = Bp + (long)k0 * ldb;
      #pragma unroll
      for (int i = 0; i < 4; ++i) {
        const int t4 = tid + i * 256;
        const int kr = t4 >> 5, n4 = t4 & 31;      // 32 float4 per 128-wide k-row
        const float4 f = *(const float4*)(Bq + (long)kr * ldb + n4 * 4);
        Bs[n4 * 4 + 0][kr] = f2h(f.x);
        Bs[n4 * 4 + 1][kr] = f2h(f.y);
        Bs[n4 * 4 + 2][kr] = f2h(f.z);
        Bs[n4 * 4 + 3][kr] = f2h(f.w);
      }
    }
    __syncthreads();
    f16x8 fa[4], fb[4];
    #pragma unroll
    for (int m = 0; m < 4; ++m) fa[m] = *(const f16x8*)&As[wr * 64 + m * 16 + lrow][kseg * 8];
    #pragma unroll
    for (int n = 0; n < 4; ++n) fb[n] = *(const f16x8*)&Bs[wc * 64 + n * 16 + lrow][kseg * 8];
    #pragma unroll
    for (int m = 0; m < 4; ++m)
      #pragma unroll
      for (int n = 0; n < 4; ++n)
        acc[m][n] = __builtin_amdgcn_mfma_f32_16x16x32_f16(fa[m], fb[n], acc[m][n], 0, 0, 0);
    __syncthreads();
  }
  #pragma unroll
  for (int m = 0; m < 4; ++m)
    #pragma unroll
    for (int n = 0; n < 4; ++n)
      #pragma unroll
      for (int i = 0; i < 4; ++i) {
        const int r = m0 + wr * 64 + m * 16 + kseg * 4 + i;  // C/D: row=(lane>>4)*4+i
        const int c = n0 + wc * 64 + n * 16 + lrow;          //      col=lane&15 (m89)
        Cp[(long)r * ldc + c] = acc[m][n][i];
      }
}

// ---------------------------------------------------------------------------
// i/f gate projections: per token, 16 dot products over E=2048, soft-capped.
// ---------------------------------------------------------------------------
__global__ __launch_bounds__(256) void proj_if_kernel(
    const float* __restrict__ x, const float* __restrict__ Wi, const float* __restrict__ bi,
    const float* __restrict__ Wf, const float* __restrict__ bfg,
    float* __restrict__ ip, float* __restrict__ fp)
{
  const int tok = blockIdx.x;
  const int tid = threadIdx.x;
  const float* xr = x + (long)tok * EMB;
  float ai[8] = {}, af[8] = {};
  #pragma unroll
  for (int j = 0; j < 8; ++j) {
    const int e = tid + j * 256;
    const float xe = xr[e];
    const float4* wi4 = (const float4*)(Wi + (long)e * 8);
    const float4* wf4 = (const float4*)(Wf + (long)e * 8);
    const float4 a0 = wi4[0], a1 = wi4[1], b0 = wf4[0], b1 = wf4[1];
    ai[0] += xe * a0.x; ai[1] += xe * a0.y; ai[2] += xe * a0.z; ai[3] += xe * a0.w;
    ai[4] += xe * a1.x; ai[5] += xe * a1.y; ai[6] += xe * a1.z; ai[7] += xe * a1.w;
    af[0] += xe * b0.x; af[1] += xe * b0.y; af[2] += xe * b0.z; af[3] += xe * b0.w;
    af[4] += xe * b1.x; af[5] += xe * b1.y; af[6] += xe * b1.z; af[7] += xe * b1.w;
  }
  #pragma unroll
  for (int hh = 0; hh < 8; ++hh)
    for (int off = 32; off; off >>= 1) {
      ai[hh] += __shfl_xor(ai[hh], off);
      af[hh] += __shfl_xor(af[hh], off);
    }
  __shared__ float red[4][16];
  const int lane = tid & 63, wid = tid >> 6;
  if (lane == 0) {
    #pragma unroll
    for (int hh = 0; hh < 8; ++hh) { red[wid][hh] = ai[hh]; red[wid][hh + 8] = af[hh]; }
  }
  __syncthreads();
  if (tid < 16) {
    const float v = red[0][tid] + red[1][tid] + red[2][tid] + red[3][tid];
    const int b = tok >> 10, s = tok & 1023;
    if (tid < 8) {
      const float zv = v + bi[tid];
      ip[(long)(b * NH_ + tid) * S_LEN + s] = 15.0f * tanhf(zv * (1.0f / 15.0f));
    } else {
      const int hh = tid - 8;
      const float zv = v + bfg[hh];
      fp[(long)(b * NH_ + hh) * S_LEN + s] = 15.0f * tanhf(zv * (1.0f / 15.0f));
    }
  }
}

// ---------------------------------------------------------------------------
// Per (b,h): logsigmoid, inclusive cumsum cf, a = i_pre - cf, running max m,
// vecM = cf + m.  Hillis-Steele scans in LDS, 1024 threads.
// ---------------------------------------------------------------------------
__global__ __launch_bounds__(1024) void gates_kernel(
    const float* __restrict__ fp, const float* __restrict__ ip,
    float* __restrict__ aArr, float* __restrict__ mArr, float* __restrict__ vMArr)
{
  const int bh = blockIdx.x;
  const int s = threadIdx.x;
  __shared__ float sh[1024];
  const float f = fp[(long)bh * S_LEN + s];
  const float lsg = fminf(f, 0.0f) - log1pf(expf(-fabsf(f)));  // log_sigmoid
  float v = lsg;
  sh[s] = v; __syncthreads();
  for (int off = 1; off < 1024; off <<= 1) {
    const float o = (s >= off) ? sh[s - off] : 0.0f;
    __syncthreads();
    v += o; sh[s] = v;
    __syncthreads();
  }
  const float cf = v;
  const float a = ip[(long)bh * S_LEN + s] - cf;
  v = a;
  sh[s] = v; __syncthreads();
  for (int off = 1; off < 1024; off <<= 1) {
    const float o = (s >= off) ? sh[s - off] : -3.0e38f;
    __syncthreads();
    v = fmaxf(v, o); sh[s] = v;
    __syncthreads();
  }
  aArr[(long)bh * S_LEN + s] = a;
  mArr[(long)bh * S_LEN + s] = v;
  vMArr[(long)bh * S_LEN + s] = cf + v;
}

// ---------------------------------------------------------------------------
// ATT1: per (b,h, 128-row tile): W[s,t] = (q.k^T)/16 * exp(a[t]-m[s]) (causal),
// stored f16; row sums -> invn = 1/(max(|sum|, exp(-vecM)) + eps).
// ---------------------------------------------------------------------------
__global__ __launch_bounds__(256) void att1_kernel(
    const float* __restrict__ q, const float* __restrict__ kk,
    const float* __restrict__ aArr, const float* __restrict__ mArr,
    const float* __restrict__ vMArr, _Float16* __restrict__ W, float* __restrict__ invn)
{
  __shared__ _Float16 Qs[128][40];
  __shared__ _Float16 Ks[128][40];
  __shared__ float nsh[2][128];
  const int tid = threadIdx.x;
  const int m0 = blockIdx.x * 128;
  const int bh = blockIdx.y;
  const int b = bh >> 3, h = bh & 7;
  const float* Aq = q + (long)b * S_LEN * EMB + h * DH_;   // row s, lda=EMB
  const float* Ak = kk + (long)b * S_LEN * DH_;            // row t, lda=DH_
  const float* aA = aArr + (long)bh * S_LEN;
  const float* mA = mArr + (long)bh * S_LEN;
  const int lane = tid & 63, wid = tid >> 6;
  const int wr = wid >> 1, wc = wid & 1;
  const int lrow = lane & 15, kseg = lane >> 4;

  float m_s[4][4];
  #pragma unroll
  for (int m = 0; m < 4; ++m)
    #pragma unroll
    for (int i = 0; i < 4; ++i)
      m_s[m][i] = mA[m0 + wr * 64 + m * 16 + kseg * 4 + i];

  float nacc[4][4] = {};
  for (int n0 = 0; n0 <= m0; n0 += 128) {
    f32x4 acc[4][4] = {};
    for (int k0 = 0; k0 < DH_; k0 += 32) {
      #pragma unroll
      for (int i = 0; i < 4; ++i) {
        const int t4 = tid + i * 256;
        const int row = t4 >> 3, c4 = t4 & 7;
        const float4 f = *(const float4*)(Aq + (long)(m0 + row) * EMB + k0 + c4 * 4);
        f16x4 h4 = {f2h(f.x), f2h(f.y), f2h(f.z), f2h(f.w)};
        *(f16x4*)&Qs[row][c4 * 4] = h4;
        const float4 g = *(const float4*)(Ak + (long)(n0 + row) * DH_ + k0 + c4 * 4);
        f16x4 h5 = {f2h(g.x), f2h(g.y), f2h(g.z), f2h(g.w)};
        *(f16x4*)&Ks[row][c4 * 4] = h5;
      }
      __syncthreads();
      f16x8 fa[4], fb[4];
      #pragma unroll
      for (int m = 0; m < 4; ++m) fa[m] = *(const f16x8*)&Qs[wr * 64 + m * 16 + lrow][kseg * 8];
      #pragma unroll
      for (int n = 0; n < 4; ++n) fb[n] = *(const f16x8*)&Ks[wc * 64 + n * 16 + lrow][kseg * 8];
      #pragma unroll
      for (int m = 0; m < 4; ++m)
        #pragma unroll
        for (int n = 0; n < 4; ++n)
          acc[m][n] = __builtin_amdgcn_mfma_f32_16x16x32_f16(fa[m], fb[n], acc[m][n], 0, 0, 0);
      __syncthreads();
    }
    float a_t[4];
    #pragma unroll
    for (int n = 0; n < 4; ++n) a_t[n] = aA[n0 + wc * 64 + n * 16 + lrow];
    #pragma unroll
    for (int m = 0; m < 4; ++m)
      #pragma unroll
      for (int n = 0; n < 4; ++n)
        #pragma unroll
        for (int i = 0; i < 4; ++i) {
          const int s = m0 + wr * 64 + m * 16 + kseg * 4 + i;
          const int t = n0 + wc * 64 + n * 16 + lrow;
          float w = 0.0f;
          if (t <= s) w = acc[m][n][i] * 0.0625f * expf(a_t[n] - m_s[m][i]);
          nacc[m][i] += w;
          W[((long)bh * S_LEN + s) * S_LEN + t] = f2h(w);
        }
  }
  // row-sum across the 16-lane col group
  #pragma unroll
  for (int m = 0; m < 4; ++m)
    #pragma unroll
    for (int i = 0; i < 4; ++i) {
      float v = nacc[m][i];
      v += __shfl_xor(v, 1); v += __shfl_xor(v, 2);
      v += __shfl_xor(v, 4); v += __shfl_xor(v, 8);
      nacc[m][i] = v;
    }
  if (lrow == 0) {
    #pragma unroll
    for (int m = 0; m < 4; ++m)
      #pragma unroll
      for (int i = 0; i < 4; ++i)
        nsh[wc][wr * 64 + m * 16 + kseg * 4 + i] = nacc[m][i];
  }
  __syncthreads();
  if (tid < 128) {
    const int s = m0 + tid;
    const float tot = nsh[0][tid] + nsh[1][tid];
    const float vm = vMArr[(long)bh * S_LEN + s];
    const float vecN = fmaxf(fabsf(tot), expf(-vm));
    invn[(long)bh * S_LEN + s] = 1.0f / (vecN + 1e-6f);
  }
}

// ---------------------------------------------------------------------------
// Per (token, head): scale by invn, LN over DH=256 (f32), *gamma, *sigmoid(o).
// ---------------------------------------------------------------------------
__global__ __launch_bounds__(256) void ln_gate_kernel(
    const float* __restrict__ hbuf, const float* __restrict__ invn,
    const float* __restrict__ opre, const float* __restrict__ gamma,
    float* __restrict__ u)
{
  const int tok = blockIdx.x;
  const int hh = blockIdx.y;
  const int b = tok >> 10, s = tok & 1023;
  const int d = threadIdx.x;
  const int bh = b * NH_ + hh;
  const float val = hbuf[((long)bh * S_LEN + s) * DH_ + d] * invn[(long)bh * S_LEN + s];
  float s1 = val, s2 = val * val;
  for (int off = 32; off; off >>= 1) { s1 += __shfl_xor(s1, off); s2 += __shfl_xor(s2, off); }
  __shared__ float r1[4], r2[4];
  const int wid = threadIdx.x >> 6, lane = threadIdx.x & 63;
  if (lane == 0) { r1[wid] = s1; r2[wid] = s2; }
  __syncthreads();
  s1 = r1[0] + r1[1] + r1[2] + r1[3];
  s2 = r2[0] + r2[1] + r2[2] + r2[3];
  const float mu = s1 * (1.0f / 256.0f);
  const float var = s2 * (1.0f / 256.0f) - mu * mu;
  const float hn = (val - mu) * rsqrtf(var + 1e-6f) * gamma[hh * DH_ + d];
  const float o = opre[(long)tok * EMB + hh * DH_ + d];
  u[(long)tok * EMB + hh * DH_ + d] = hn * (1.0f / (1.0f + expf(-o)));
}

// ---------------------------------------------------------------------------
extern "C" void kernel_launch(void* const* d_in, const int* in_sizes, int n_in,
                              void* d_out, int out_size, void* d_ws, size_t ws_size,
                              hipStream_t stream)
{
  (void)in_sizes; (void)n_in; (void)out_size; (void)ws_size;
  const float* x     = (const float*)d_in[0];
  const float* Wq    = (const float*)d_in[1];
  const float* Wk    = (const float*)d_in[2];
  const float* Wv    = (const float*)d_in[3];
  const float* Wog   = (const float*)d_in[4];
  const float* Wi    = (const float*)d_in[5];
  const float* bi    = (const float*)d_in[6];
  const float* Wf    = (const float*)d_in[7];
  const float* bfg   = (const float*)d_in[8];
  const float* gamma = (const float*)d_in[9];
  const float* Wout  = (const float*)d_in[10];

  char* base = (char*)d_ws;
  size_t off = 0;
  auto take = [&](size_t bytes) -> char* {
    char* p = base + off;
    off += (bytes + 255) & ~(size_t)255;
    return p;
  };
  float*    qb = (float*)take((size_t)TOKENS * EMB * 4);          // 16 MB
  float*    ob = (float*)take((size_t)TOKENS * EMB * 4);          // 16 MB
  float*    kb = (float*)take((size_t)TOKENS * DH_ * 4);          //  2 MB
  float*    vb = (float*)take((size_t)TOKENS * DH_ * 4);          //  2 MB
  float*    hb = (float*)take((size_t)NBH * S_LEN * DH_ * 4);     // 16 MB
  _Float16* Wb = (_Float16*)take((size_t)NBH * S_LEN * S_LEN * 2);// 32 MB
  float*    ip = (float*)take((size_t)NBH * S_LEN * 4);
  float*    fp = (float*)take((size_t)NBH * S_LEN * 4);
  float*    aA = (float*)take((size_t)NBH * S_LEN * 4);
  float*    mA = (float*)take((size_t)NBH * S_LEN * 4);
  float*    vM = (float*)take((size_t)NBH * S_LEN * 4);
  float*    nv = (float*)take((size_t)NBH * S_LEN * 4);
  float*    ub = qb;  // q dead after att1; reuse for gated/normed activations
  float*    y  = (float*)d_out;

  const dim3 blk(256);
  // projections
  gemm_kernel<false><<<dim3(EMB / 128, TOKENS / 128, 1), blk, 0, stream>>>(
      x, Wq, qb, EMB, EMB, EMB, EMB, 0L, 0L, 0L, 1, 0);
  gemm_kernel<false><<<dim3(DH_ / 128, TOKENS / 128, 1), blk, 0, stream>>>(
      x, Wk, kb, EMB, EMB, DH_, DH_, 0L, 0L, 0L, 1, 0);
  gemm_kernel<false><<<dim3(DH_ / 128, TOKENS / 128, 1), blk, 0, stream>>>(
      x, Wv, vb, EMB, EMB, DH_, DH_, 0L, 0L, 0L, 1, 0);
  gemm_kernel<false><<<dim3(EMB / 128, TOKENS / 128, 1), blk, 0, stream>>>(
      x, Wog, ob, EMB, EMB, EMB, EMB, 0L, 0L, 0L, 1, 0);
  proj_if_kernel<<<dim3(TOKENS), blk, 0, stream>>>(x, Wi, bi, Wf, bfg, ip, fp);
  gates_kernel<<<dim3(NBH), dim3(1024), 0, stream>>>(fp, ip, aA, mA, vM);
  // mLSTM backend
  att1_kernel<<<dim3(S_LEN / 128, NBH), blk, 0, stream>>>(qb, kb, aA, mA, vM, Wb, nv);
  gemm_kernel<true><<<dim3(DH_ / 128, S_LEN / 128, NBH), blk, 0, stream>>>(
      Wb, vb, hb, S_LEN, S_LEN, DH_, DH_,
      (long)S_LEN * S_LEN, (long)S_LEN * DH_, (long)S_LEN * DH_, NH_, 1);
  // layernorm + output gate
  ln_gate_kernel<<<dim3(TOKENS, NH_), blk, 0, stream>>>(hb, nv, ob, gamma, ub);
  // output projection
  gemm_kernel<false><<<dim3(EMB / 128, TOKENS / 128, 1), blk, 0, stream>>>(
      ub, Wout, y, EMB, EMB, EMB, EMB, 0L, 0L, 0L, 1, 0);
}

// Round 3
// 248.397 us; speedup vs baseline: 3.2360x; 3.2360x over previous
//
#include <hip/hip_runtime.h>
#include <math.h>

#define S_LEN  1024
#define EMB    2048
#define NH_    8
#define DH_    256
#define TOKENS 2048   // B*S
#define NBH    16     // B*NH
#define NQKVO  4608   // 2048 q | 256 k | 256 v | 2048 o

typedef __attribute__((ext_vector_type(4))) float    f32x4;
typedef __attribute__((ext_vector_type(8))) _Float16 f16x8;
typedef __attribute__((ext_vector_type(4))) _Float16 f16x4;

__device__ __forceinline__ _Float16 f2h(float f) { return (_Float16)f; }

// async global->LDS, 16B per lane; LDS dest = wave-uniform base + lane*16
__device__ __forceinline__ void gload16(const void* g, void* l) {
  __builtin_amdgcn_global_load_lds(
      (const __attribute__((address_space(1))) void*)g,
      (__attribute__((address_space(3))) void*)l, 16, 0, 0);
}

// ---------------------------------------------------------------------------
// f32->f16 cast, 8 elems/thread
// ---------------------------------------------------------------------------
__global__ __launch_bounds__(256) void cast_f16_kernel(
    const float* __restrict__ in, _Float16* __restrict__ out, long n)
{
  const long i = ((long)blockIdx.x * 256 + threadIdx.x) * 8;
  if (i >= n) return;
  const float4 a = *(const float4*)(in + i);
  const float4 b = *(const float4*)(in + i + 4);
  f16x8 o = {f2h(a.x), f2h(a.y), f2h(a.z), f2h(a.w),
             f2h(b.x), f2h(b.y), f2h(b.z), f2h(b.w)};
  *(f16x8*)(out + i) = o;
}

// ---------------------------------------------------------------------------
// Tiled transpose + cast to f16: out[z*sOut + c*ldo + r] = in[z*sIn + r*ldi + c]
// grid = (C/64, R/64, Z), block 256.
// ---------------------------------------------------------------------------
template<typename TIN>
__global__ __launch_bounds__(256) void transpose_cast_kernel(
    const TIN* __restrict__ in, long ldi, _Float16* __restrict__ out, long ldo,
    long sIn, long sOut)
{
  __shared__ float t[64][65];
  const int lx = threadIdx.x & 63, ly = threadIdx.x >> 6;
  const long r0 = (long)blockIdx.y * 64, c0 = (long)blockIdx.x * 64;
  const TIN* ip = in + (long)blockIdx.z * sIn;
  _Float16* op = out + (long)blockIdx.z * sOut;
  #pragma unroll
  for (int i = 0; i < 16; ++i)
    t[ly + i * 4][lx] = (float)ip[(r0 + ly + i * 4) * ldi + c0 + lx];
  __syncthreads();
  #pragma unroll
  for (int i = 0; i < 16; ++i)
    op[(c0 + ly + i * 4) * ldo + r0 + lx] = f2h(t[lx][ly + i * 4]);
}

// ---------------------------------------------------------------------------
// f16 GEMM, both operands K-contiguous ("B^T" layout):
//   C[M,N] = A[M,K] @ Bt[N,K]^T.  128x128 tile, BK=32, 4 waves (2x2),
//   global_load_lds width-16 staging (m97 structure). CT = f16 or f32.
// causal!=0 limits K to m0+128 (for h = W @ V with lower-tri W).
// ---------------------------------------------------------------------------
template<typename CT>
__global__ __launch_bounds__(256) void gemm_bt_kernel(
    const _Float16* __restrict__ Ag, const _Float16* __restrict__ Btg,
    CT* __restrict__ Cg, int K, int lda, int ldb, int ldc,
    long sA, long sB, long sC, int zdivB, int causal)
{
  __shared__ _Float16 As[128 * 32];
  __shared__ _Float16 Bs[128 * 32];
  const int tid = threadIdx.x;
  const int lane = tid & 63, wid = tid >> 6;
  const int n0 = blockIdx.x * 128;
  const int m0 = blockIdx.y * 128;
  const int z  = blockIdx.z;
  const _Float16* Ap = Ag + (long)z * sA + (long)m0 * lda;
  const _Float16* Bp = Btg + (long)(z / zdivB) * sB + (long)n0 * ldb;
  const int wr = wid >> 1, wc = wid & 1;
  const int lrow = lane & 15, kseg = lane >> 4;
  const int kl = causal ? ((m0 + 128 < K) ? m0 + 128 : K) : K;
  const int crow = lane >> 2, cc = (lane & 3) * 8;   // 16 rows x 4 16B-chunks per wave-group

  f32x4 acc[4][4] = {};
  for (int k0 = 0; k0 < kl; k0 += 32) {
    #pragma unroll
    for (int i = 0; i < 2; ++i) {
      const int cbase = (i * 4 + wid) * 64;          // chunk index base
      const int row = (cbase >> 2) + crow;
      gload16(Ap + (long)row * lda + k0 + cc, (char*)As + cbase * 16);
      gload16(Bp + (long)row * ldb + k0 + cc, (char*)Bs + cbase * 16);
    }
    __syncthreads();
    f16x8 fa[4], fb[4];
    #pragma unroll
    for (int m = 0; m < 4; ++m) fa[m] = *(const f16x8*)&As[(wr * 64 + m * 16 + lrow) * 32 + kseg * 8];
    #pragma unroll
    for (int n = 0; n < 4; ++n) fb[n] = *(const f16x8*)&Bs[(wc * 64 + n * 16 + lrow) * 32 + kseg * 8];
    #pragma unroll
    for (int m = 0; m < 4; ++m)
      #pragma unroll
      for (int n = 0; n < 4; ++n)
        acc[m][n] = __builtin_amdgcn_mfma_f32_16x16x32_f16(fa[m], fb[n], acc[m][n], 0, 0, 0);
    __syncthreads();
  }
  CT* Cp = Cg + (long)z * sC;
  #pragma unroll
  for (int m = 0; m < 4; ++m)
    #pragma unroll
    for (int n = 0; n < 4; ++n)
      #pragma unroll
      for (int i = 0; i < 4; ++i) {
        const int r = m0 + wr * 64 + m * 16 + kseg * 4 + i;  // row=(lane>>4)*4+i (m89)
        const int c = n0 + wc * 64 + n * 16 + lrow;          // col=lane&15
        Cp[(long)r * ldc + c] = (CT)acc[m][n][i];
      }
}

// ---------------------------------------------------------------------------
// i/f gate projections: per token, 16 dot products over E=2048, soft-capped.
// ---------------------------------------------------------------------------
__global__ __launch_bounds__(256) void proj_if_kernel(
    const float* __restrict__ x, const float* __restrict__ Wi, const float* __restrict__ bi,
    const float* __restrict__ Wf, const float* __restrict__ bfg,
    float* __restrict__ ip, float* __restrict__ fp)
{
  const int tok = blockIdx.x;
  const int tid = threadIdx.x;
  const float* xr = x + (long)tok * EMB;
  float ai[8] = {}, af[8] = {};
  #pragma unroll
  for (int j = 0; j < 8; ++j) {
    const int e = tid + j * 256;
    const float xe = xr[e];
    const float4* wi4 = (const float4*)(Wi + (long)e * 8);
    const float4* wf4 = (const float4*)(Wf + (long)e * 8);
    const float4 a0 = wi4[0], a1 = wi4[1], b0 = wf4[0], b1 = wf4[1];
    ai[0] += xe * a0.x; ai[1] += xe * a0.y; ai[2] += xe * a0.z; ai[3] += xe * a0.w;
    ai[4] += xe * a1.x; ai[5] += xe * a1.y; ai[6] += xe * a1.z; ai[7] += xe * a1.w;
    af[0] += xe * b0.x; af[1] += xe * b0.y; af[2] += xe * b0.z; af[3] += xe * b0.w;
    af[4] += xe * b1.x; af[5] += xe * b1.y; af[6] += xe * b1.z; af[7] += xe * b1.w;
  }
  #pragma unroll
  for (int hh = 0; hh < 8; ++hh)
    for (int off = 32; off; off >>= 1) {
      ai[hh] += __shfl_xor(ai[hh], off);
      af[hh] += __shfl_xor(af[hh], off);
    }
  __shared__ float red[4][16];
  const int lane = tid & 63, wid = tid >> 6;
  if (lane == 0) {
    #pragma unroll
    for (int hh = 0; hh < 8; ++hh) { red[wid][hh] = ai[hh]; red[wid][hh + 8] = af[hh]; }
  }
  __syncthreads();
  if (tid < 16) {
    const float v = red[0][tid] + red[1][tid] + red[2][tid] + red[3][tid];
    const int b = tok >> 10, s = tok & 1023;
    if (tid < 8) {
      const float zv = v + bi[tid];
      ip[(long)(b * NH_ + tid) * S_LEN + s] = 15.0f * tanhf(zv * (1.0f / 15.0f));
    } else {
      const int hh = tid - 8;
      const float zv = v + bfg[hh];
      fp[(long)(b * NH_ + hh) * S_LEN + s] = 15.0f * tanhf(zv * (1.0f / 15.0f));
    }
  }
}

// ---------------------------------------------------------------------------
// Per (b,h): logsigmoid, cumsum cf, a = i_pre - cf, running max m, vecM = cf+m.
// ---------------------------------------------------------------------------
__global__ __launch_bounds__(1024) void gates_kernel(
    const float* __restrict__ fp, const float* __restrict__ ip,
    float* __restrict__ aArr, float* __restrict__ mArr, float* __restrict__ vMArr)
{
  const int bh = blockIdx.x;
  const int s = threadIdx.x;
  __shared__ float sh[1024];
  const float f = fp[(long)bh * S_LEN + s];
  const float lsg = fminf(f, 0.0f) - log1pf(expf(-fabsf(f)));  // log_sigmoid
  float v = lsg;
  sh[s] = v; __syncthreads();
  for (int off = 1; off < 1024; off <<= 1) {
    const float o = (s >= off) ? sh[s - off] : 0.0f;
    __syncthreads();
    v += o; sh[s] = v;
    __syncthreads();
  }
  const float cf = v;
  const float a = ip[(long)bh * S_LEN + s] - cf;
  v = a;
  sh[s] = v; __syncthreads();
  for (int off = 1; off < 1024; off <<= 1) {
    const float o = (s >= off) ? sh[s - off] : -3.0e38f;
    __syncthreads();
    v = fmaxf(v, o); sh[s] = v;
    __syncthreads();
  }
  aArr[(long)bh * S_LEN + s] = a;
  mArr[(long)bh * S_LEN + s] = v;
  vMArr[(long)bh * S_LEN + s] = cf + v;
}

// ---------------------------------------------------------------------------
// ATT1: 64-row tiles. W[s,t] = (q.k^T)/16 * exp(a[t]-m[s]) (causal), f16;
// row sums -> invn. Q hoisted to LDS once (XOR-swizzled vs 32-way conflict).
// Qs layout: 64 rows x 32 chunks(16B); LDS[row][slot] = G[row][slot^(row&7)].
// ---------------------------------------------------------------------------
__global__ __launch_bounds__(256) void att1_kernel(
    const _Float16* __restrict__ qkvo,
    const float* __restrict__ aArr, const float* __restrict__ mArr,
    const float* __restrict__ vMArr, _Float16* __restrict__ W, float* __restrict__ invn)
{
  __shared__ _Float16 Qs[64 * 256];
  __shared__ _Float16 Ks[128 * 32];
  __shared__ float nsh[2][64];
  const int tid = threadIdx.x;
  const int lane = tid & 63, wid = tid >> 6;
  const int r0 = blockIdx.x * 64;
  const int bh = blockIdx.y;
  const int b = bh >> 3, h = bh & 7;
  const _Float16* Qg = qkvo + (long)(b * S_LEN) * NQKVO + h * DH_;
  const _Float16* Kg = qkvo + (long)(b * S_LEN) * NQKVO + 2048;
  const float* aA = aArr + (long)bh * S_LEN;
  const float* mA = mArr + (long)bh * S_LEN;
  const int wr = wid >> 1, wc = wid & 1;   // 2x2 waves: 32 rows x 64 cols each
  const int lrow = lane & 15, kseg = lane >> 4;

  // stage Q[64][256]: 2048 16B-chunks, 8 iters x 256 lanes.
  // chunk c: row = c>>5 (32 chunks/row), slot = c&31; source chunk = slot^(row&7).
  #pragma unroll
  for (int i = 0; i < 8; ++i) {
    const int cbase = (i * 4 + wid) * 64;          // wave-uniform
    const int c = cbase + lane;
    const int row = c >> 5, slot = c & 31;
    const int gs = slot ^ (row & 7);
    gload16(Qg + (long)(r0 + row) * NQKVO + gs * 8, (char*)Qs + cbase * 16);
  }

  float m_s[2][4];
  #pragma unroll
  for (int m = 0; m < 2; ++m)
    #pragma unroll
    for (int i = 0; i < 4; ++i)
      m_s[m][i] = mA[r0 + wr * 32 + m * 16 + kseg * 4 + i];

  const int crow = lane >> 2, cc = (lane & 3) * 8;
  float nacc[2][4] = {};
  for (int n0 = 0; n0 <= r0; n0 += 128) {
    f32x4 acc[2][4] = {};
    for (int k0 = 0; k0 < DH_; k0 += 32) {
      #pragma unroll
      for (int i = 0; i < 2; ++i) {
        const int cbase = (i * 4 + wid) * 64;
        const int row = (cbase >> 2) + crow;
        gload16(Kg + (long)(n0 + row) * NQKVO + k0 + cc, (char*)Ks + cbase * 16);
      }
      __syncthreads();   // first barrier also drains the Q-stage (vmcnt(0))
      f16x8 fa[2], fb[4];
      #pragma unroll
      for (int m = 0; m < 2; ++m) {
        const int qrow = wr * 32 + m * 16 + lrow;
        const int kchunk = (k0 >> 3) + kseg;       // 16B-chunk index, 0..31
        fa[m] = *(const f16x8*)&Qs[qrow * 256 + ((kchunk ^ (qrow & 7)) << 3)];
      }
      #pragma unroll
      for (int n = 0; n < 4; ++n) fb[n] = *(const f16x8*)&Ks[(wc * 64 + n * 16 + lrow) * 32 + kseg * 8];
      #pragma unroll
      for (int m = 0; m < 2; ++m)
        #pragma unroll
        for (int n = 0; n < 4; ++n)
          acc[m][n] = __builtin_amdgcn_mfma_f32_16x16x32_f16(fa[m], fb[n], acc[m][n], 0, 0, 0);
      __syncthreads();
    }
    float a_t[4];
    #pragma unroll
    for (int n = 0; n < 4; ++n) a_t[n] = aA[n0 + wc * 64 + n * 16 + lrow];
    #pragma unroll
    for (int m = 0; m < 2; ++m)
      #pragma unroll
      for (int n = 0; n < 4; ++n)
        #pragma unroll
        for (int i = 0; i < 4; ++i) {
          const int s = r0 + wr * 32 + m * 16 + kseg * 4 + i;
          const int t = n0 + wc * 64 + n * 16 + lrow;
          float w = 0.0f;
          if (t <= s) w = acc[m][n][i] * 0.0625f * expf(a_t[n] - m_s[m][i]);
          nacc[m][i] += w;
          W[((long)bh * S_LEN + s) * S_LEN + t] = f2h(w);
        }
  }
  #pragma unroll
  for (int m = 0; m < 2; ++m)
    #pragma unroll
    for (int i = 0; i < 4; ++i) {
      float v = nacc[m][i];
      v += __shfl_xor(v, 1); v += __shfl_xor(v, 2);
      v += __shfl_xor(v, 4); v += __shfl_xor(v, 8);
      nacc[m][i] = v;
    }
  __syncthreads();
  if (lrow == 0) {
    #pragma unroll
    for (int m = 0; m < 2; ++m)
      #pragma unroll
      for (int i = 0; i < 4; ++i)
        nsh[wc][wr * 32 + m * 16 + kseg * 4 + i] = nacc[m][i];
  }
  __syncthreads();
  if (tid < 64) {
    const int s = r0 + tid;
    const float tot = nsh[0][tid] + nsh[1][tid];
    const float vm = vMArr[(long)bh * S_LEN + s];
    const float vecN = fmaxf(fabsf(tot), expf(-vm));
    invn[(long)bh * S_LEN + s] = 1.0f / (vecN + 1e-6f);
  }
}

// ---------------------------------------------------------------------------
// One wave per (token, head) row: scale by invn, LN over DH=256 (f32),
// *gamma, *sigmoid(o); writes f16.
// ---------------------------------------------------------------------------
__global__ __launch_bounds__(256) void ln_gate_kernel(
    const float* __restrict__ hbuf, const float* __restrict__ invn,
    const _Float16* __restrict__ qkvo, const float* __restrict__ gamma,
    _Float16* __restrict__ u)
{
  const int wid = threadIdx.x >> 6, lane = threadIdx.x & 63;
  const int row = blockIdx.x * 4 + wid;   // row = tok*8 + h
  const int tok = row >> 3, h = row & 7;
  const int b = tok >> 10, s = tok & 1023;
  const int bh = b * NH_ + h;
  const float inv = invn[(long)bh * S_LEN + s];
  const float4 hv = *(const float4*)(hbuf + ((long)bh * S_LEN + s) * DH_ + lane * 4);
  const float v0 = hv.x * inv, v1 = hv.y * inv, v2 = hv.z * inv, v3 = hv.w * inv;
  float s1 = v0 + v1 + v2 + v3;
  float s2 = v0 * v0 + v1 * v1 + v2 * v2 + v3 * v3;
  for (int off = 32; off; off >>= 1) { s1 += __shfl_xor(s1, off); s2 += __shfl_xor(s2, off); }
  const float mu = s1 * (1.0f / 256.0f);
  const float var = s2 * (1.0f / 256.0f) - mu * mu;
  const float rs = rsqrtf(var + 1e-6f);
  const float4 g = *(const float4*)(gamma + h * DH_ + lane * 4);
  const f16x4 ov = *(const f16x4*)(qkvo + (long)tok * NQKVO + 2560 + h * DH_ + lane * 4);
  f16x4 res;
  res[0] = f2h((v0 - mu) * rs * g.x * (1.0f / (1.0f + expf(-(float)ov[0]))));
  res[1] = f2h((v1 - mu) * rs * g.y * (1.0f / (1.0f + expf(-(float)ov[1]))));
  res[2] = f2h((v2 - mu) * rs * g.z * (1.0f / (1.0f + expf(-(float)ov[2]))));
  res[3] = f2h((v3 - mu) * rs * g.w * (1.0f / (1.0f + expf(-(float)ov[3]))));
  *(f16x4*)(u + (long)tok * EMB + h * DH_ + lane * 4) = res;
}

// ---------------------------------------------------------------------------
extern "C" void kernel_launch(void* const* d_in, const int* in_sizes, int n_in,
                              void* d_out, int out_size, void* d_ws, size_t ws_size,
                              hipStream_t stream)
{
  (void)in_sizes; (void)n_in; (void)out_size; (void)ws_size;
  const float* x     = (const float*)d_in[0];
  const float* Wq    = (const float*)d_in[1];
  const float* Wk    = (const float*)d_in[2];
  const float* Wv    = (const float*)d_in[3];
  const float* Wog   = (const float*)d_in[4];
  const float* Wi    = (const float*)d_in[5];
  const float* bi    = (const float*)d_in[6];
  const float* Wf    = (const float*)d_in[7];
  const float* bfg   = (const float*)d_in[8];
  const float* gamma = (const float*)d_in[9];
  const float* Wout  = (const float*)d_in[10];

  char* base = (char*)d_ws;
  size_t off = 0;
  auto take = [&](size_t bytes) -> char* {
    char* p = base + off;
    off += (bytes + 255) & ~(size_t)255;
    return p;
  };
  _Float16* xh    = (_Float16*)take((size_t)TOKENS * EMB * 2);        //  8 MB
  _Float16* WcatT = (_Float16*)take((size_t)NQKVO * EMB * 2);         // 19 MB
  _Float16* WoutT = (_Float16*)take((size_t)EMB * EMB * 2);           //  8 MB
  _Float16* qkvo  = (_Float16*)take((size_t)TOKENS * NQKVO * 2);      // 19 MB
  _Float16* vt    = (_Float16*)take((size_t)2 * DH_ * S_LEN * 2);     //  1 MB
  _Float16* Wb    = (_Float16*)take((size_t)NBH * S_LEN * S_LEN * 2); // 32 MB
  float*    hb    = (float*)take((size_t)NBH * S_LEN * DH_ * 4);      // 16 MB
  float*    ip    = (float*)take((size_t)NBH * S_LEN * 4);
  float*    fp    = (float*)take((size_t)NBH * S_LEN * 4);
  float*    aA    = (float*)take((size_t)NBH * S_LEN * 4);
  float*    mA    = (float*)take((size_t)NBH * S_LEN * 4);
  float*    vM    = (float*)take((size_t)NBH * S_LEN * 4);
  float*    nv    = (float*)take((size_t)NBH * S_LEN * 4);
  _Float16* ub    = xh;   // xh dead after QKVO GEMM
  float*    y     = (float*)d_out;

  const dim3 blk(256);
  // --- one-time casts / transposes ---
  cast_f16_kernel<<<dim3((TOKENS * EMB) / (256 * 8)), blk, 0, stream>>>(x, xh, (long)TOKENS * EMB);
  transpose_cast_kernel<float><<<dim3(32, 32), blk, 0, stream>>>(Wq,   EMB, WcatT,                     EMB, 0L, 0L);
  transpose_cast_kernel<float><<<dim3( 4, 32), blk, 0, stream>>>(Wk,   DH_, WcatT + (long)2048 * EMB,  EMB, 0L, 0L);
  transpose_cast_kernel<float><<<dim3( 4, 32), blk, 0, stream>>>(Wv,   DH_, WcatT + (long)2304 * EMB,  EMB, 0L, 0L);
  transpose_cast_kernel<float><<<dim3(32, 32), blk, 0, stream>>>(Wog,  EMB, WcatT + (long)2560 * EMB,  EMB, 0L, 0L);
  transpose_cast_kernel<float><<<dim3(32, 32), blk, 0, stream>>>(Wout, EMB, WoutT,                     EMB, 0L, 0L);
  // --- fused QKVO projection: [2048,4608] = xh @ WcatT^T ---
  gemm_bt_kernel<_Float16><<<dim3(NQKVO / 128, TOKENS / 128, 1), blk, 0, stream>>>(
      xh, WcatT, qkvo, EMB, EMB, EMB, NQKVO, 0L, 0L, 0L, 1, 0);
  // --- V^T per batch for ATT2 ---
  transpose_cast_kernel<_Float16><<<dim3(4, 16, 2), blk, 0, stream>>>(
      qkvo + 2304, NQKVO, vt, S_LEN, (long)S_LEN * NQKVO, (long)DH_ * S_LEN);
  // --- gates ---
  proj_if_kernel<<<dim3(TOKENS), blk, 0, stream>>>(x, Wi, bi, Wf, bfg, ip, fp);
  gates_kernel<<<dim3(NBH), dim3(1024), 0, stream>>>(fp, ip, aA, mA, vM);
  // --- mLSTM backend ---
  att1_kernel<<<dim3(S_LEN / 64, NBH), blk, 0, stream>>>(qkvo, aA, mA, vM, Wb, nv);
  gemm_bt_kernel<float><<<dim3(DH_ / 128, S_LEN / 128, NBH), blk, 0, stream>>>(
      Wb, vt, hb, S_LEN, S_LEN, S_LEN, DH_,
      (long)S_LEN * S_LEN, (long)DH_ * S_LEN, (long)S_LEN * DH_, NH_, 1);
  // --- layernorm + output gate ---
  ln_gate_kernel<<<dim3(TOKENS * NH_ / 4), blk, 0, stream>>>(hb, nv, qkvo, gamma, ub);
  // --- output projection ---
  gemm_bt_kernel<float><<<dim3(EMB / 128, TOKENS / 128, 1), blk, 0, stream>>>(
      ub, WoutT, y, EMB, EMB, EMB, EMB, 0L, 0L, 0L, 1, 0);
}

// Round 4
// 220.674 us; speedup vs baseline: 3.6425x; 1.1256x over previous
//
#include <hip/hip_runtime.h>
#include <math.h>

#define S_LEN  1024
#define EMB    2048
#define NH_    8
#define DH_    256
#define TOKENS 2048   // B*S
#define NBH    16     // B*NH
#define NQKVO  4608   // 2048 q | 256 k | 256 v | 2048 o

typedef __attribute__((ext_vector_type(4))) float    f32x4;
typedef __attribute__((ext_vector_type(8))) _Float16 f16x8;
typedef __attribute__((ext_vector_type(4))) _Float16 f16x4;

__device__ __forceinline__ _Float16 f2h(float f) { return (_Float16)f; }

// async global->LDS, 16B per lane; LDS dest = wave-uniform base + lane*16
__device__ __forceinline__ void gload16(const void* g, void* l) {
  __builtin_amdgcn_global_load_lds(
      (const __attribute__((address_space(1))) void*)g,
      (__attribute__((address_space(3))) void*)l, 16, 0, 0);
}

// ---------------------------------------------------------------------------
// f32->f16 cast, 8 elems/thread
// ---------------------------------------------------------------------------
__global__ __launch_bounds__(256) void cast_f16_kernel(
    const float* __restrict__ in, _Float16* __restrict__ out, long n)
{
  const long i = ((long)blockIdx.x * 256 + threadIdx.x) * 8;
  if (i >= n) return;
  const float4 a = *(const float4*)(in + i);
  const float4 b = *(const float4*)(in + i + 4);
  f16x8 o = {f2h(a.x), f2h(a.y), f2h(a.z), f2h(a.w),
             f2h(b.x), f2h(b.y), f2h(b.z), f2h(b.w)};
  *(f16x8*)(out + i) = o;
}

// ---------------------------------------------------------------------------
// Tiled transpose + cast to f16: out[z*sOut + c*ldo + r] = in[z*sIn + r*ldi + c]
// ---------------------------------------------------------------------------
template<typename TIN>
__global__ __launch_bounds__(256) void transpose_cast_kernel(
    const TIN* __restrict__ in, long ldi, _Float16* __restrict__ out, long ldo,
    long sIn, long sOut)
{
  __shared__ float t[64][65];
  const int lx = threadIdx.x & 63, ly = threadIdx.x >> 6;
  const long r0 = (long)blockIdx.y * 64, c0 = (long)blockIdx.x * 64;
  const TIN* ip = in + (long)blockIdx.z * sIn;
  _Float16* op = out + (long)blockIdx.z * sOut;
  #pragma unroll
  for (int i = 0; i < 16; ++i)
    t[ly + i * 4][lx] = (float)ip[(r0 + ly + i * 4) * ldi + c0 + lx];
  __syncthreads();
  #pragma unroll
  for (int i = 0; i < 16; ++i)
    op[(c0 + ly + i * 4) * ldo + r0 + lx] = f2h(t[lx][ly + i * 4]);
}

// ---------------------------------------------------------------------------
// f16 GEMM, both operands K-contiguous: C[M,N] = A[M,K] @ Bt[N,K]^T.
// 128x128 tile, BK=32, 4 waves (2x2). 2-phase double-buffered staging:
// stage tile k+1 before computing tile k; counted vmcnt(4) (never 0 mid-loop),
// raw s_barrier (no compiler vmcnt(0) drain).  CT = f16 or f32.
// ---------------------------------------------------------------------------
template<typename CT>
__global__ __launch_bounds__(256) void gemm_bt_kernel(
    const _Float16* __restrict__ Ag, const _Float16* __restrict__ Btg,
    CT* __restrict__ Cg, int K, int lda, int ldb, int ldc,
    long sA, long sB, long sC, int zdivB, int causal)
{
  __shared__ _Float16 As[2][128 * 32];
  __shared__ _Float16 Bs[2][128 * 32];
  const int tid = threadIdx.x;
  const int lane = tid & 63, wid = tid >> 6;
  const int n0 = blockIdx.x * 128;
  const int m0 = blockIdx.y * 128;
  const int z  = blockIdx.z;
  const _Float16* Ap = Ag + (long)z * sA + (long)m0 * lda;
  const _Float16* Bp = Btg + (long)(z / zdivB) * sB + (long)n0 * ldb;
  const int wr = wid >> 1, wc = wid & 1;
  const int lrow = lane & 15, kseg = lane >> 4;
  const int kl = causal ? ((m0 + 128 < K) ? m0 + 128 : K) : K;
  const int crow = lane >> 2, cc = (lane & 3) * 8;   // 16 rows x 4 16B-chunks per wave-group

  auto stage = [&](int b, int k0) {
    #pragma unroll
    for (int i = 0; i < 2; ++i) {
      const int cbase = (i * 4 + wid) * 64;
      const int row = (cbase >> 2) + crow;
      gload16(Ap + (long)row * lda + k0 + cc, (char*)As[b] + cbase * 16);
      gload16(Bp + (long)row * ldb + k0 + cc, (char*)Bs[b] + cbase * 16);
    }
  };

  f32x4 acc[4][4] = {};
  stage(0, 0);
  int buf = 0;
  for (int k0 = 0; k0 < kl; k0 += 32) {
    if (k0 + 32 < kl) {
      stage(buf ^ 1, k0 + 32);                       // prefetch next tile
      asm volatile("s_waitcnt vmcnt(4)" ::: "memory"); // cur's 4 loads done; next's in flight
    } else {
      asm volatile("s_waitcnt vmcnt(0)" ::: "memory");
    }
    __builtin_amdgcn_s_barrier();
    __builtin_amdgcn_sched_barrier(0);
    f16x8 fa[4], fb[4];
    #pragma unroll
    for (int m = 0; m < 4; ++m) fa[m] = *(const f16x8*)&As[buf][(wr * 64 + m * 16 + lrow) * 32 + kseg * 8];
    #pragma unroll
    for (int n = 0; n < 4; ++n) fb[n] = *(const f16x8*)&Bs[buf][(wc * 64 + n * 16 + lrow) * 32 + kseg * 8];
    #pragma unroll
    for (int m = 0; m < 4; ++m)
      #pragma unroll
      for (int n = 0; n < 4; ++n)
        acc[m][n] = __builtin_amdgcn_mfma_f32_16x16x32_f16(fa[m], fb[n], acc[m][n], 0, 0, 0);
    __builtin_amdgcn_s_barrier();                    // reads done before next stage overwrites
    buf ^= 1;
  }
  CT* Cp = Cg + (long)z * sC;
  #pragma unroll
  for (int m = 0; m < 4; ++m)
    #pragma unroll
    for (int n = 0; n < 4; ++n)
      #pragma unroll
      for (int i = 0; i < 4; ++i) {
        const int r = m0 + wr * 64 + m * 16 + kseg * 4 + i;  // row=(lane>>4)*4+i (m89)
        const int c = n0 + wc * 64 + n * 16 + lrow;          // col=lane&15
        Cp[(long)r * ldc + c] = (CT)acc[m][n][i];
      }
}

// ---------------------------------------------------------------------------
// i/f gate projections: per token, 16 dot products over E=2048, soft-capped.
// ---------------------------------------------------------------------------
__global__ __launch_bounds__(256) void proj_if_kernel(
    const float* __restrict__ x, const float* __restrict__ Wi, const float* __restrict__ bi,
    const float* __restrict__ Wf, const float* __restrict__ bfg,
    float* __restrict__ ip, float* __restrict__ fp)
{
  const int tok = blockIdx.x;
  const int tid = threadIdx.x;
  const float* xr = x + (long)tok * EMB;
  float ai[8] = {}, af[8] = {};
  #pragma unroll
  for (int j = 0; j < 8; ++j) {
    const int e = tid + j * 256;
    const float xe = xr[e];
    const float4* wi4 = (const float4*)(Wi + (long)e * 8);
    const float4* wf4 = (const float4*)(Wf + (long)e * 8);
    const float4 a0 = wi4[0], a1 = wi4[1], b0 = wf4[0], b1 = wf4[1];
    ai[0] += xe * a0.x; ai[1] += xe * a0.y; ai[2] += xe * a0.z; ai[3] += xe * a0.w;
    ai[4] += xe * a1.x; ai[5] += xe * a1.y; ai[6] += xe * a1.z; ai[7] += xe * a1.w;
    af[0] += xe * b0.x; af[1] += xe * b0.y; af[2] += xe * b0.z; af[3] += xe * b0.w;
    af[4] += xe * b1.x; af[5] += xe * b1.y; af[6] += xe * b1.z; af[7] += xe * b1.w;
  }
  #pragma unroll
  for (int hh = 0; hh < 8; ++hh)
    for (int off = 32; off; off >>= 1) {
      ai[hh] += __shfl_xor(ai[hh], off);
      af[hh] += __shfl_xor(af[hh], off);
    }
  __shared__ float red[4][16];
  const int lane = tid & 63, wid = tid >> 6;
  if (lane == 0) {
    #pragma unroll
    for (int hh = 0; hh < 8; ++hh) { red[wid][hh] = ai[hh]; red[wid][hh + 8] = af[hh]; }
  }
  __syncthreads();
  if (tid < 16) {
    const float v = red[0][tid] + red[1][tid] + red[2][tid] + red[3][tid];
    const int b = tok >> 10, s = tok & 1023;
    if (tid < 8) {
      const float zv = v + bi[tid];
      ip[(long)(b * NH_ + tid) * S_LEN + s] = 15.0f * tanhf(zv * (1.0f / 15.0f));
    } else {
      const int hh = tid - 8;
      const float zv = v + bfg[hh];
      fp[(long)(b * NH_ + hh) * S_LEN + s] = 15.0f * tanhf(zv * (1.0f / 15.0f));
    }
  }
}

// ---------------------------------------------------------------------------
// Per (b,h): logsigmoid, cumsum cf, a = i_pre - cf, running max m, vecM = cf+m.
// ---------------------------------------------------------------------------
__global__ __launch_bounds__(1024) void gates_kernel(
    const float* __restrict__ fp, const float* __restrict__ ip,
    float* __restrict__ aArr, float* __restrict__ mArr, float* __restrict__ vMArr)
{
  const int bh = blockIdx.x;
  const int s = threadIdx.x;
  __shared__ float sh[1024];
  const float f = fp[(long)bh * S_LEN + s];
  const float lsg = fminf(f, 0.0f) - log1pf(expf(-fabsf(f)));  // log_sigmoid
  float v = lsg;
  sh[s] = v; __syncthreads();
  for (int off = 1; off < 1024; off <<= 1) {
    const float o = (s >= off) ? sh[s - off] : 0.0f;
    __syncthreads();
    v += o; sh[s] = v;
    __syncthreads();
  }
  const float cf = v;
  const float a = ip[(long)bh * S_LEN + s] - cf;
  v = a;
  sh[s] = v; __syncthreads();
  for (int off = 1; off < 1024; off <<= 1) {
    const float o = (s >= off) ? sh[s - off] : -3.0e38f;
    __syncthreads();
    v = fmaxf(v, o); sh[s] = v;
    __syncthreads();
  }
  aArr[(long)bh * S_LEN + s] = a;
  mArr[(long)bh * S_LEN + s] = v;
  vMArr[(long)bh * S_LEN + s] = cf + v;
}

// ---------------------------------------------------------------------------
// Fused mLSTM attention: per (bh, 64-row q-tile), loop over 128-wide t-tiles:
//   phase1: S = QK^T/16, w = S*exp(a[t]-m[s]) causal -> Ws (LDS, swizzled f16),
//           accumulate row sums
//   phase2: PV: hacc[64x256] += Ws @ V^T (vt staged per 32-t chunk)
// Epilogue: invn from row sums, h = hacc*invn -> f16.
// No S x S matrix materialized in HBM.
// ---------------------------------------------------------------------------
__global__ __launch_bounds__(256) void att_fused_kernel(
    const _Float16* __restrict__ qkvo, const _Float16* __restrict__ vt,
    const float* __restrict__ aArr, const float* __restrict__ mArr,
    const float* __restrict__ vMArr, _Float16* __restrict__ hb)
{
  __shared__ _Float16 Qs[64 * 256];   // swizzled (32 chunks/row, ^ (row&7))
  __shared__ _Float16 Ks[128 * 32];
  __shared__ _Float16 Vs[256 * 32];   // [d][t-chunk], t contiguous
  __shared__ _Float16 Ws[64 * 128];   // swizzled (16 chunks/row, ^ ((row&7)<<1))
  __shared__ float nsh[2][64];
  __shared__ float invs[64];
  const int tid = threadIdx.x;
  const int lane = tid & 63, wid = tid >> 6;
  const int r0 = blockIdx.x * 64;
  const int bh = blockIdx.y;
  const int b = bh >> 3, h = bh & 7;
  const _Float16* Qg = qkvo + (long)(b * S_LEN) * NQKVO + h * DH_;
  const _Float16* Kg = qkvo + (long)(b * S_LEN) * NQKVO + 2048;
  const _Float16* Vtb = vt + (long)b * DH_ * S_LEN;
  const float* aA = aArr + (long)bh * S_LEN;
  const float* mA = mArr + (long)bh * S_LEN;
  const int wr = wid >> 1, wc = wid & 1;
  const int lrow = lane & 15, kseg = lane >> 4;
  const int crow = lane >> 2, cc = (lane & 3) * 8;

  // stage Q[64][256]: 2048 chunks; row=c>>5, slot=c&31, src chunk = slot^(row&7)
  #pragma unroll
  for (int i = 0; i < 8; ++i) {
    const int cbase = (i * 4 + wid) * 64;
    const int c = cbase + lane;
    const int row = c >> 5, slot = c & 31;
    gload16(Qg + (long)(r0 + row) * NQKVO + (slot ^ (row & 7)) * 8, (char*)Qs + cbase * 16);
  }

  float m_s[2][4];
  #pragma unroll
  for (int m = 0; m < 2; ++m)
    #pragma unroll
    for (int i = 0; i < 4; ++i)
      m_s[m][i] = mA[r0 + wr * 32 + m * 16 + kseg * 4 + i];

  f32x4 hacc[2][8] = {};       // PV acc: 32 rows x 128 d per wave
  float nacc[2][4] = {};
  for (int n0 = 0; n0 <= r0; n0 += 128) {
    // ---- phase 1: QK^T over DH=256 ----
    f32x4 acc[2][4] = {};
    for (int k0 = 0; k0 < DH_; k0 += 32) {
      #pragma unroll
      for (int i = 0; i < 2; ++i) {
        const int cbase = (i * 4 + wid) * 64;
        const int row = (cbase >> 2) + crow;
        gload16(Kg + (long)(n0 + row) * NQKVO + k0 + cc, (char*)Ks + cbase * 16);
      }
      __syncthreads();
      f16x8 fa[2], fb[4];
      #pragma unroll
      for (int m = 0; m < 2; ++m) {
        const int qrow = wr * 32 + m * 16 + lrow;
        const int kchunk = (k0 >> 3) + kseg;
        fa[m] = *(const f16x8*)&Qs[qrow * 256 + ((kchunk ^ (qrow & 7)) << 3)];
      }
      #pragma unroll
      for (int n = 0; n < 4; ++n) fb[n] = *(const f16x8*)&Ks[(wc * 64 + n * 16 + lrow) * 32 + kseg * 8];
      #pragma unroll
      for (int m = 0; m < 2; ++m)
        #pragma unroll
        for (int n = 0; n < 4; ++n)
          acc[m][n] = __builtin_amdgcn_mfma_f32_16x16x32_f16(fa[m], fb[n], acc[m][n], 0, 0, 0);
      __syncthreads();
    }
    // ---- weighting + store W-tile to LDS (swizzled) ----
    float a_t[4];
    #pragma unroll
    for (int n = 0; n < 4; ++n) a_t[n] = aA[n0 + wc * 64 + n * 16 + lrow];
    #pragma unroll
    for (int m = 0; m < 2; ++m)
      #pragma unroll
      for (int n = 0; n < 4; ++n)
        #pragma unroll
        for (int i = 0; i < 4; ++i) {
          const int sr = wr * 32 + m * 16 + kseg * 4 + i;   // local row 0..63
          const int t  = wc * 64 + n * 16 + lrow;           // local col 0..127
          float w = 0.0f;
          if (n0 + t <= r0 + sr) w = acc[m][n][i] * 0.0625f * expf(a_t[n] - m_s[m][i]);
          nacc[m][i] += w;
          Ws[sr * 128 + ((((t >> 3) ^ ((sr & 7) << 1))) << 3) + (t & 7)] = f2h(w);
        }
    __syncthreads();
    // ---- phase 2: PV over this 128-t tile, 32-t steps ----
    for (int kt = 0; kt < 128; kt += 32) {
      #pragma unroll
      for (int i = 0; i < 4; ++i) {          // stage Vs[256 d][32 t]
        const int cbase = (i * 4 + wid) * 64;
        const int c = cbase + lane;
        const int d = c >> 2, tc = c & 3;
        gload16(Vtb + (long)d * S_LEN + n0 + kt + tc * 8, (char*)Vs + cbase * 16);
      }
      __syncthreads();
      f16x8 wa[2], vb[8];
      #pragma unroll
      for (int m = 0; m < 2; ++m) {
        const int row = wr * 32 + m * 16 + lrow;
        const int chunk = (kt >> 3) + kseg;
        wa[m] = *(const f16x8*)&Ws[row * 128 + ((chunk ^ ((row & 7) << 1)) << 3)];
      }
      #pragma unroll
      for (int n = 0; n < 8; ++n) vb[n] = *(const f16x8*)&Vs[(wc * 128 + n * 16 + lrow) * 32 + kseg * 8];
      #pragma unroll
      for (int m = 0; m < 2; ++m)
        #pragma unroll
        for (int n = 0; n < 8; ++n)
          hacc[m][n] = __builtin_amdgcn_mfma_f32_16x16x32_f16(wa[m], vb[n], hacc[m][n], 0, 0, 0);
      __syncthreads();
    }
  }
  // ---- row sums -> invn ----
  #pragma unroll
  for (int m = 0; m < 2; ++m)
    #pragma unroll
    for (int i = 0; i < 4; ++i) {
      float v = nacc[m][i];
      v += __shfl_xor(v, 1); v += __shfl_xor(v, 2);
      v += __shfl_xor(v, 4); v += __shfl_xor(v, 8);
      nacc[m][i] = v;
    }
  if (lrow == 0) {
    #pragma unroll
    for (int m = 0; m < 2; ++m)
      #pragma unroll
      for (int i = 0; i < 4; ++i)
        nsh[wc][wr * 32 + m * 16 + kseg * 4 + i] = nacc[m][i];
  }
  __syncthreads();
  if (tid < 64) {
    const float tot = nsh[0][tid] + nsh[1][tid];
    const float vm = vMArr[(long)bh * S_LEN + r0 + tid];
    const float vecN = fmaxf(fabsf(tot), expf(-vm));
    invs[tid] = 1.0f / (vecN + 1e-6f);
  }
  __syncthreads();
  // ---- scaled h write (f16) ----
  #pragma unroll
  for (int m = 0; m < 2; ++m)
    #pragma unroll
    for (int n = 0; n < 8; ++n)
      #pragma unroll
      for (int i = 0; i < 4; ++i) {
        const int row = wr * 32 + m * 16 + kseg * 4 + i;
        const int d = wc * 128 + n * 16 + lrow;
        hb[((long)bh * S_LEN + r0 + row) * DH_ + d] = f2h(hacc[m][n][i] * invs[row]);
      }
}

// ---------------------------------------------------------------------------
// One wave per (token, head) row: LN over DH=256 (f32), *gamma, *sigmoid(o).
// ---------------------------------------------------------------------------
__global__ __launch_bounds__(256) void ln_gate_kernel(
    const _Float16* __restrict__ hbuf,
    const _Float16* __restrict__ qkvo, const float* __restrict__ gamma,
    _Float16* __restrict__ u)
{
  const int wid = threadIdx.x >> 6, lane = threadIdx.x & 63;
  const int row = blockIdx.x * 4 + wid;   // row = tok*8 + h
  const int tok = row >> 3, h = row & 7;
  const int b = tok >> 10, s = tok & 1023;
  const int bh = b * NH_ + h;
  const f16x4 hv = *(const f16x4*)(hbuf + ((long)bh * S_LEN + s) * DH_ + lane * 4);
  const float v0 = (float)hv[0], v1 = (float)hv[1], v2 = (float)hv[2], v3 = (float)hv[3];
  float s1 = v0 + v1 + v2 + v3;
  float s2 = v0 * v0 + v1 * v1 + v2 * v2 + v3 * v3;
  for (int off = 32; off; off >>= 1) { s1 += __shfl_xor(s1, off); s2 += __shfl_xor(s2, off); }
  const float mu = s1 * (1.0f / 256.0f);
  const float var = s2 * (1.0f / 256.0f) - mu * mu;
  const float rs = rsqrtf(var + 1e-6f);
  const float4 g = *(const float4*)(gamma + h * DH_ + lane * 4);
  const f16x4 ov = *(const f16x4*)(qkvo + (long)tok * NQKVO + 2560 + h * DH_ + lane * 4);
  f16x4 res;
  res[0] = f2h((v0 - mu) * rs * g.x * (1.0f / (1.0f + expf(-(float)ov[0]))));
  res[1] = f2h((v1 - mu) * rs * g.y * (1.0f / (1.0f + expf(-(float)ov[1]))));
  res[2] = f2h((v2 - mu) * rs * g.z * (1.0f / (1.0f + expf(-(float)ov[2]))));
  res[3] = f2h((v3 - mu) * rs * g.w * (1.0f / (1.0f + expf(-(float)ov[3]))));
  *(f16x4*)(u + (long)tok * EMB + h * DH_ + lane * 4) = res;
}

// ---------------------------------------------------------------------------
extern "C" void kernel_launch(void* const* d_in, const int* in_sizes, int n_in,
                              void* d_out, int out_size, void* d_ws, size_t ws_size,
                              hipStream_t stream)
{
  (void)in_sizes; (void)n_in; (void)out_size; (void)ws_size;
  const float* x     = (const float*)d_in[0];
  const float* Wq    = (const float*)d_in[1];
  const float* Wk    = (const float*)d_in[2];
  const float* Wv    = (const float*)d_in[3];
  const float* Wog   = (const float*)d_in[4];
  const float* Wi    = (const float*)d_in[5];
  const float* bi    = (const float*)d_in[6];
  const float* Wf    = (const float*)d_in[7];
  const float* bfg   = (const float*)d_in[8];
  const float* gamma = (const float*)d_in[9];
  const float* Wout  = (const float*)d_in[10];

  char* base = (char*)d_ws;
  size_t off = 0;
  auto take = [&](size_t bytes) -> char* {
    char* p = base + off;
    off += (bytes + 255) & ~(size_t)255;
    return p;
  };
  _Float16* xh    = (_Float16*)take((size_t)TOKENS * EMB * 2);        //  8 MB
  _Float16* WcatT = (_Float16*)take((size_t)NQKVO * EMB * 2);         // 19 MB
  _Float16* WoutT = (_Float16*)take((size_t)EMB * EMB * 2);           //  8 MB
  _Float16* qkvo  = (_Float16*)take((size_t)TOKENS * NQKVO * 2);      // 19 MB
  _Float16* vt    = (_Float16*)take((size_t)2 * DH_ * S_LEN * 2);     //  1 MB
  _Float16* hb    = (_Float16*)take((size_t)NBH * S_LEN * DH_ * 2);   //  8 MB
  float*    ip    = (float*)take((size_t)NBH * S_LEN * 4);
  float*    fp    = (float*)take((size_t)NBH * S_LEN * 4);
  float*    aA    = (float*)take((size_t)NBH * S_LEN * 4);
  float*    mA    = (float*)take((size_t)NBH * S_LEN * 4);
  float*    vM    = (float*)take((size_t)NBH * S_LEN * 4);
  _Float16* ub    = xh;   // xh dead after QKVO GEMM
  float*    y     = (float*)d_out;

  const dim3 blk(256);
  // --- one-time casts / transposes ---
  cast_f16_kernel<<<dim3((TOKENS * EMB) / (256 * 8)), blk, 0, stream>>>(x, xh, (long)TOKENS * EMB);
  transpose_cast_kernel<float><<<dim3(32, 32), blk, 0, stream>>>(Wq,   EMB, WcatT,                     EMB, 0L, 0L);
  transpose_cast_kernel<float><<<dim3( 4, 32), blk, 0, stream>>>(Wk,   DH_, WcatT + (long)2048 * EMB,  EMB, 0L, 0L);
  transpose_cast_kernel<float><<<dim3( 4, 32), blk, 0, stream>>>(Wv,   DH_, WcatT + (long)2304 * EMB,  EMB, 0L, 0L);
  transpose_cast_kernel<float><<<dim3(32, 32), blk, 0, stream>>>(Wog,  EMB, WcatT + (long)2560 * EMB,  EMB, 0L, 0L);
  transpose_cast_kernel<float><<<dim3(32, 32), blk, 0, stream>>>(Wout, EMB, WoutT,                     EMB, 0L, 0L);
  // --- fused QKVO projection: [2048,4608] = xh @ WcatT^T ---
  gemm_bt_kernel<_Float16><<<dim3(NQKVO / 128, TOKENS / 128, 1), blk, 0, stream>>>(
      xh, WcatT, qkvo, EMB, EMB, EMB, NQKVO, 0L, 0L, 0L, 1, 0);
  // --- V^T per batch ---
  transpose_cast_kernel<_Float16><<<dim3(4, 16, 2), blk, 0, stream>>>(
      qkvo + 2304, NQKVO, vt, S_LEN, (long)S_LEN * NQKVO, (long)DH_ * S_LEN);
  // --- gates ---
  proj_if_kernel<<<dim3(TOKENS), blk, 0, stream>>>(x, Wi, bi, Wf, bfg, ip, fp);
  gates_kernel<<<dim3(NBH), dim3(1024), 0, stream>>>(fp, ip, aA, mA, vM);
  // --- fused mLSTM backend (QK^T -> D-weight -> PV -> invn scale) ---
  att_fused_kernel<<<dim3(S_LEN / 64, NBH), blk, 0, stream>>>(qkvo, vt, aA, mA, vM, hb);
  // --- layernorm + output gate ---
  ln_gate_kernel<<<dim3(TOKENS * NH_ / 4), blk, 0, stream>>>(hb, qkvo, gamma, ub);
  // --- output projection ---
  gemm_bt_kernel<float><<<dim3(EMB / 128, TOKENS / 128, 1), blk, 0, stream>>>(
      ub, WoutT, y, EMB, EMB, EMB, EMB, 0L, 0L, 0L, 1, 0);
}

// Round 5
// 210.632 us; speedup vs baseline: 3.8162x; 1.0477x over previous
//
#include <hip/hip_runtime.h>
#include <math.h>

#define S_LEN  1024
#define EMB    2048
#define NH_    8
#define DH_    256
#define TOKENS 2048   // B*S
#define NBH    16     // B*NH
#define NQKVO  4608   // 2048 q | 256 k | 256 v | 2048 o

typedef __attribute__((ext_vector_type(4))) float    f32x4;
typedef __attribute__((ext_vector_type(8))) _Float16 f16x8;
typedef __attribute__((ext_vector_type(4))) _Float16 f16x4;

__device__ __forceinline__ _Float16 f2h(float f) { return (_Float16)f; }

// async global->LDS, 16B per lane; LDS dest = wave-uniform base + lane*16
__device__ __forceinline__ void gload16(const void* g, void* l) {
  __builtin_amdgcn_global_load_lds(
      (const __attribute__((address_space(1))) void*)g,
      (__attribute__((address_space(3))) void*)l, 16, 0, 0);
}

// ---------------------------------------------------------------------------
// f32->f16 cast, 8 elems/thread
// ---------------------------------------------------------------------------
__global__ __launch_bounds__(256) void cast_f16_kernel(
    const float* __restrict__ in, _Float16* __restrict__ out, long n)
{
  const long i = ((long)blockIdx.x * 256 + threadIdx.x) * 8;
  if (i >= n) return;
  const float4 a = *(const float4*)(in + i);
  const float4 b = *(const float4*)(in + i + 4);
  f16x8 o = {f2h(a.x), f2h(a.y), f2h(a.z), f2h(a.w),
             f2h(b.x), f2h(b.y), f2h(b.z), f2h(b.w)};
  *(f16x8*)(out + i) = o;
}

// ---------------------------------------------------------------------------
// Tiled transpose + cast to f16: out[z*sOut + c*ldo + r] = in[z*sIn + r*ldi + c]
// ---------------------------------------------------------------------------
template<typename TIN>
__global__ __launch_bounds__(256) void transpose_cast_kernel(
    const TIN* __restrict__ in, long ldi, _Float16* __restrict__ out, long ldo,
    long sIn, long sOut)
{
  __shared__ float t[64][65];
  const int lx = threadIdx.x & 63, ly = threadIdx.x >> 6;
  const long r0 = (long)blockIdx.y * 64, c0 = (long)blockIdx.x * 64;
  const TIN* ip = in + (long)blockIdx.z * sIn;
  _Float16* op = out + (long)blockIdx.z * sOut;
  #pragma unroll
  for (int i = 0; i < 16; ++i)
    t[ly + i * 4][lx] = (float)ip[(r0 + ly + i * 4) * ldi + c0 + lx];
  __syncthreads();
  #pragma unroll
  for (int i = 0; i < 16; ++i)
    op[(c0 + ly + i * 4) * ldo + r0 + lx] = f2h(t[lx][ly + i * 4]);
}

// ---------------------------------------------------------------------------
// f16 GEMM, both operands K-contiguous: C[M,N] = A[M,K] @ Bt[N,K]^T.
// 128x128 tile, BK=32, 4 waves (2x2). 2-phase double-buffered staging with
// counted vmcnt (never 0 mid-loop).  CT = f16 or f32.
// ---------------------------------------------------------------------------
template<typename CT>
__global__ __launch_bounds__(256) void gemm_bt_kernel(
    const _Float16* __restrict__ Ag, const _Float16* __restrict__ Btg,
    CT* __restrict__ Cg, int K, int lda, int ldb, int ldc,
    long sA, long sB, long sC, int zdivB, int causal)
{
  __shared__ _Float16 As[2][128 * 32];
  __shared__ _Float16 Bs[2][128 * 32];
  const int tid = threadIdx.x;
  const int lane = tid & 63, wid = tid >> 6;
  const int n0 = blockIdx.x * 128;
  const int m0 = blockIdx.y * 128;
  const int z  = blockIdx.z;
  const _Float16* Ap = Ag + (long)z * sA + (long)m0 * lda;
  const _Float16* Bp = Btg + (long)(z / zdivB) * sB + (long)n0 * ldb;
  const int wr = wid >> 1, wc = wid & 1;
  const int lrow = lane & 15, kseg = lane >> 4;
  const int kl = causal ? ((m0 + 128 < K) ? m0 + 128 : K) : K;
  const int crow = lane >> 2, cc = (lane & 3) * 8;   // 16 rows x 4 16B-chunks per wave-group

  auto stage = [&](int b, int k0) {
    #pragma unroll
    for (int i = 0; i < 2; ++i) {
      const int cbase = (i * 4 + wid) * 64;
      const int row = (cbase >> 2) + crow;
      gload16(Ap + (long)row * lda + k0 + cc, (char*)As[b] + cbase * 16);
      gload16(Bp + (long)row * ldb + k0 + cc, (char*)Bs[b] + cbase * 16);
    }
  };

  f32x4 acc[4][4] = {};
  stage(0, 0);
  int buf = 0;
  for (int k0 = 0; k0 < kl; k0 += 32) {
    if (k0 + 32 < kl) {
      stage(buf ^ 1, k0 + 32);                       // prefetch next tile
      asm volatile("s_waitcnt vmcnt(4)" ::: "memory"); // cur's 4 loads done; next's in flight
    } else {
      asm volatile("s_waitcnt vmcnt(0)" ::: "memory");
    }
    __builtin_amdgcn_s_barrier();
    __builtin_amdgcn_sched_barrier(0);
    f16x8 fa[4], fb[4];
    #pragma unroll
    for (int m = 0; m < 4; ++m) fa[m] = *(const f16x8*)&As[buf][(wr * 64 + m * 16 + lrow) * 32 + kseg * 8];
    #pragma unroll
    for (int n = 0; n < 4; ++n) fb[n] = *(const f16x8*)&Bs[buf][(wc * 64 + n * 16 + lrow) * 32 + kseg * 8];
    #pragma unroll
    for (int m = 0; m < 4; ++m)
      #pragma unroll
      for (int n = 0; n < 4; ++n)
        acc[m][n] = __builtin_amdgcn_mfma_f32_16x16x32_f16(fa[m], fb[n], acc[m][n], 0, 0, 0);
    __builtin_amdgcn_s_barrier();                    // reads done before next stage overwrites
    buf ^= 1;
  }
  CT* Cp = Cg + (long)z * sC;
  #pragma unroll
  for (int m = 0; m < 4; ++m)
    #pragma unroll
    for (int n = 0; n < 4; ++n)
      #pragma unroll
      for (int i = 0; i < 4; ++i) {
        const int r = m0 + wr * 64 + m * 16 + kseg * 4 + i;  // row=(lane>>4)*4+i (m89)
        const int c = n0 + wc * 64 + n * 16 + lrow;          // col=lane&15
        Cp[(long)r * ldc + c] = (CT)acc[m][n][i];
      }
}

// ---------------------------------------------------------------------------
// i/f gate projections: per token, 16 dot products over E=2048, soft-capped.
// ---------------------------------------------------------------------------
__global__ __launch_bounds__(256) void proj_if_kernel(
    const float* __restrict__ x, const float* __restrict__ Wi, const float* __restrict__ bi,
    const float* __restrict__ Wf, const float* __restrict__ bfg,
    float* __restrict__ ip, float* __restrict__ fp)
{
  const int tok = blockIdx.x;
  const int tid = threadIdx.x;
  const float* xr = x + (long)tok * EMB;
  float ai[8] = {}, af[8] = {};
  #pragma unroll
  for (int j = 0; j < 8; ++j) {
    const int e = tid + j * 256;
    const float xe = xr[e];
    const float4* wi4 = (const float4*)(Wi + (long)e * 8);
    const float4* wf4 = (const float4*)(Wf + (long)e * 8);
    const float4 a0 = wi4[0], a1 = wi4[1], b0 = wf4[0], b1 = wf4[1];
    ai[0] += xe * a0.x; ai[1] += xe * a0.y; ai[2] += xe * a0.z; ai[3] += xe * a0.w;
    ai[4] += xe * a1.x; ai[5] += xe * a1.y; ai[6] += xe * a1.z; ai[7] += xe * a1.w;
    af[0] += xe * b0.x; af[1] += xe * b0.y; af[2] += xe * b0.z; af[3] += xe * b0.w;
    af[4] += xe * b1.x; af[5] += xe * b1.y; af[6] += xe * b1.z; af[7] += xe * b1.w;
  }
  #pragma unroll
  for (int hh = 0; hh < 8; ++hh)
    for (int off = 32; off; off >>= 1) {
      ai[hh] += __shfl_xor(ai[hh], off);
      af[hh] += __shfl_xor(af[hh], off);
    }
  __shared__ float red[4][16];
  const int lane = tid & 63, wid = tid >> 6;
  if (lane == 0) {
    #pragma unroll
    for (int hh = 0; hh < 8; ++hh) { red[wid][hh] = ai[hh]; red[wid][hh + 8] = af[hh]; }
  }
  __syncthreads();
  if (tid < 16) {
    const float v = red[0][tid] + red[1][tid] + red[2][tid] + red[3][tid];
    const int b = tok >> 10, s = tok & 1023;
    if (tid < 8) {
      const float zv = v + bi[tid];
      ip[(long)(b * NH_ + tid) * S_LEN + s] = 15.0f * tanhf(zv * (1.0f / 15.0f));
    } else {
      const int hh = tid - 8;
      const float zv = v + bfg[hh];
      fp[(long)(b * NH_ + hh) * S_LEN + s] = 15.0f * tanhf(zv * (1.0f / 15.0f));
    }
  }
}

// ---------------------------------------------------------------------------
// Per (b,h): logsigmoid, cumsum cf, a = i_pre - cf, running max m, vecM = cf+m.
// ---------------------------------------------------------------------------
__global__ __launch_bounds__(1024) void gates_kernel(
    const float* __restrict__ fp, const float* __restrict__ ip,
    float* __restrict__ aArr, float* __restrict__ mArr, float* __restrict__ vMArr)
{
  const int bh = blockIdx.x;
  const int s = threadIdx.x;
  __shared__ float sh[1024];
  const float f = fp[(long)bh * S_LEN + s];
  const float lsg = fminf(f, 0.0f) - log1pf(expf(-fabsf(f)));  // log_sigmoid
  float v = lsg;
  sh[s] = v; __syncthreads();
  for (int off = 1; off < 1024; off <<= 1) {
    const float o = (s >= off) ? sh[s - off] : 0.0f;
    __syncthreads();
    v += o; sh[s] = v;
    __syncthreads();
  }
  const float cf = v;
  const float a = ip[(long)bh * S_LEN + s] - cf;
  v = a;
  sh[s] = v; __syncthreads();
  for (int off = 1; off < 1024; off <<= 1) {
    const float o = (s >= off) ? sh[s - off] : -3.0e38f;
    __syncthreads();
    v = fmaxf(v, o); sh[s] = v;
    __syncthreads();
  }
  aArr[(long)bh * S_LEN + s] = a;
  mArr[(long)bh * S_LEN + s] = v;
  vMArr[(long)bh * S_LEN + s] = cf + v;
}

// ---------------------------------------------------------------------------
// Fused mLSTM attention, triangle-paired for causal load balance.
// Block (i, bh) owns q-subtiles qi=i and qi=31-i (32 rows each) => every
// block does exactly 9 subtile-passes.  Per 128-wide t-tile pass:
//   QK^T (K frags loaded global->reg, shared by both subtiles)
//   -> weight w = S/16 * exp(a[t]-m[s]) causal -> Ws (LDS, XOR-swizzled)
//   -> PV (V frags global->reg from vt, shared by both subtiles).
// Waves: 1x4 over t (QK) / over d (PV).  Only Q and Ws live in LDS.
// ---------------------------------------------------------------------------
__global__ __launch_bounds__(256) void att_fused_kernel(
    const _Float16* __restrict__ qkvo, const _Float16* __restrict__ vt,
    const float* __restrict__ aArr, const float* __restrict__ mArr,
    const float* __restrict__ vMArr, _Float16* __restrict__ hb)
{
  __shared__ _Float16 Qs[2][32 * 256];   // swizzled: 32 chunks/row, ^(row&7)
  __shared__ _Float16 Ws[2][32 * 128];   // swizzled: 16 chunks/row, ^((row&7)<<1)
  __shared__ float nsh[2][4][32];
  __shared__ float invs[2][32];
  const int tid = threadIdx.x;
  const int lane = tid & 63, wid = tid >> 6;
  const int bh = blockIdx.y;
  const int b = bh >> 3, h = bh & 7;
  const int r0[2] = { (int)blockIdx.x * 32, (31 - (int)blockIdx.x) * 32 };
  const _Float16* Qg = qkvo + (long)(b * S_LEN) * NQKVO + h * DH_;
  const _Float16* Kg = qkvo + (long)(b * S_LEN) * NQKVO + 2048;
  const _Float16* Vt = vt + (long)b * DH_ * S_LEN;
  const float* aA = aArr + (long)bh * S_LEN;
  const float* mA = mArr + (long)bh * S_LEN;
  const int lrow = lane & 15, kseg = lane >> 4;
  const int tbase = 32 * wid;

  // stage Q for both subtiles: 2048 chunks of 16B, 8 iters.
  // chunk c: sub=c>>10, row=(c>>5)&31, slot=c&31; src chunk = slot^(row&7).
  #pragma unroll
  for (int i = 0; i < 8; ++i) {
    const int cbase = (i * 4 + wid) * 64;   // wave-uniform; sub uniform per iter
    const int c = cbase + lane;
    const int sub = c >> 10, row = (c >> 5) & 31, slot = c & 31;
    gload16(Qg + (long)(r0[sub] + row) * NQKVO + (slot ^ (row & 7)) * 8,
            (char*)Qs + cbase * 16);
  }

  float m_s[2][2][4];
  #pragma unroll
  for (int sub = 0; sub < 2; ++sub)
    #pragma unroll
    for (int m = 0; m < 2; ++m)
      #pragma unroll
      for (int i = 0; i < 4; ++i)
        m_s[sub][m][i] = mA[r0[sub] + m * 16 + kseg * 4 + i];
  __syncthreads();   // Q staged (drains vmcnt)

  f32x4 hacc[2][2][4] = {};
  float nacc[2][2][4] = {};
  for (int n0 = 0; n0 <= r0[1]; n0 += 128) {
    // ---- QK^T: K frags global->reg, shared across subtiles ----
    f32x4 acc[2][2][2] = {};
    for (int k0 = 0; k0 < DH_; k0 += 32) {
      f16x8 fb[2];
      #pragma unroll
      for (int n = 0; n < 2; ++n)
        fb[n] = *(const f16x8*)(Kg + (long)(n0 + tbase + n * 16 + lrow) * NQKVO + k0 + kseg * 8);
      const int chunk = (k0 >> 3) + kseg;
      #pragma unroll
      for (int sub = 0; sub < 2; ++sub) {
        if (n0 > r0[sub]) continue;
        #pragma unroll
        for (int m = 0; m < 2; ++m) {
          const int qrow = m * 16 + lrow;
          const f16x8 fa = *(const f16x8*)&Qs[sub][qrow * 256 + ((chunk ^ (qrow & 7)) << 3)];
          #pragma unroll
          for (int n = 0; n < 2; ++n)
            acc[sub][m][n] = __builtin_amdgcn_mfma_f32_16x16x32_f16(fa, fb[n], acc[sub][m][n], 0, 0, 0);
        }
      }
    }
    // ---- weighting -> Ws (swizzled), row-sum accumulation ----
    float a_t[2];
    #pragma unroll
    for (int n = 0; n < 2; ++n) a_t[n] = aA[n0 + tbase + n * 16 + lrow];
    #pragma unroll
    for (int sub = 0; sub < 2; ++sub) {
      if (n0 > r0[sub]) continue;
      #pragma unroll
      for (int m = 0; m < 2; ++m)
        #pragma unroll
        for (int n = 0; n < 2; ++n)
          #pragma unroll
          for (int i = 0; i < 4; ++i) {
            const int sr = m * 16 + kseg * 4 + i;       // local row 0..31
            const int t  = tbase + n * 16 + lrow;       // local col 0..127
            float w = 0.0f;
            if (n0 + t <= r0[sub] + sr)
              w = acc[sub][m][n][i] * 0.0625f * expf(a_t[n] - m_s[sub][m][i]);
            nacc[sub][m][i] += w;
            Ws[sub][sr * 128 + (((t >> 3) ^ ((sr & 7) << 1)) << 3) + (t & 7)] = f2h(w);
          }
    }
    __syncthreads();
    // ---- PV: V frags global->reg (shared), Ws from LDS ----
    for (int kt = 0; kt < 128; kt += 32) {
      f16x8 vb[4];
      #pragma unroll
      for (int n = 0; n < 4; ++n)
        vb[n] = *(const f16x8*)(Vt + (long)(64 * wid + n * 16 + lrow) * S_LEN + n0 + kt + kseg * 8);
      const int chunk = (kt >> 3) + kseg;
      #pragma unroll
      for (int sub = 0; sub < 2; ++sub) {
        if (n0 > r0[sub]) continue;
        #pragma unroll
        for (int m = 0; m < 2; ++m) {
          const int row = m * 16 + lrow;
          const f16x8 wa = *(const f16x8*)&Ws[sub][row * 128 + ((chunk ^ ((row & 7) << 1)) << 3)];
          #pragma unroll
          for (int n = 0; n < 4; ++n)
            hacc[sub][m][n] = __builtin_amdgcn_mfma_f32_16x16x32_f16(wa, vb[n], hacc[sub][m][n], 0, 0, 0);
        }
      }
    }
    __syncthreads();   // Ws reads done before next pass overwrites
  }
  // ---- row sums -> invn (reduce across lrow, then across waves) ----
  #pragma unroll
  for (int sub = 0; sub < 2; ++sub)
    #pragma unroll
    for (int m = 0; m < 2; ++m)
      #pragma unroll
      for (int i = 0; i < 4; ++i) {
        float v = nacc[sub][m][i];
        v += __shfl_xor(v, 1); v += __shfl_xor(v, 2);
        v += __shfl_xor(v, 4); v += __shfl_xor(v, 8);
        if (lrow == 0) nsh[sub][wid][m * 16 + kseg * 4 + i] = v;
      }
  __syncthreads();
  if (tid < 64) {
    const int sub = tid >> 5, sr = tid & 31;
    const float tot = nsh[sub][0][sr] + nsh[sub][1][sr] + nsh[sub][2][sr] + nsh[sub][3][sr];
    const float vm = vMArr[(long)bh * S_LEN + r0[sub] + sr];
    const float vecN = fmaxf(fabsf(tot), expf(-vm));
    invs[sub][sr] = 1.0f / (vecN + 1e-6f);
  }
  __syncthreads();
  // ---- scaled h write (f16) ----
  #pragma unroll
  for (int sub = 0; sub < 2; ++sub)
    #pragma unroll
    for (int m = 0; m < 2; ++m)
      #pragma unroll
      for (int n = 0; n < 4; ++n)
        #pragma unroll
        for (int i = 0; i < 4; ++i) {
          const int row = m * 16 + kseg * 4 + i;
          const int d = 64 * wid + n * 16 + lrow;
          hb[((long)bh * S_LEN + r0[sub] + row) * DH_ + d] = f2h(hacc[sub][m][n][i] * invs[sub][row]);
        }
}

// ---------------------------------------------------------------------------
// One wave per (token, head) row: LN over DH=256 (f32), *gamma, *sigmoid(o).
// ---------------------------------------------------------------------------
__global__ __launch_bounds__(256) void ln_gate_kernel(
    const _Float16* __restrict__ hbuf,
    const _Float16* __restrict__ qkvo, const float* __restrict__ gamma,
    _Float16* __restrict__ u)
{
  const int wid = threadIdx.x >> 6, lane = threadIdx.x & 63;
  const int row = blockIdx.x * 4 + wid;   // row = tok*8 + h
  const int tok = row >> 3, h = row & 7;
  const int b = tok >> 10, s = tok & 1023;
  const int bh = b * NH_ + h;
  const f16x4 hv = *(const f16x4*)(hbuf + ((long)bh * S_LEN + s) * DH_ + lane * 4);
  const float v0 = (float)hv[0], v1 = (float)hv[1], v2 = (float)hv[2], v3 = (float)hv[3];
  float s1 = v0 + v1 + v2 + v3;
  float s2 = v0 * v0 + v1 * v1 + v2 * v2 + v3 * v3;
  for (int off = 32; off; off >>= 1) { s1 += __shfl_xor(s1, off); s2 += __shfl_xor(s2, off); }
  const float mu = s1 * (1.0f / 256.0f);
  const float var = s2 * (1.0f / 256.0f) - mu * mu;
  const float rs = rsqrtf(var + 1e-6f);
  const float4 g = *(const float4*)(gamma + h * DH_ + lane * 4);
  const f16x4 ov = *(const f16x4*)(qkvo + (long)tok * NQKVO + 2560 + h * DH_ + lane * 4);
  f16x4 res;
  res[0] = f2h((v0 - mu) * rs * g.x * (1.0f / (1.0f + expf(-(float)ov[0]))));
  res[1] = f2h((v1 - mu) * rs * g.y * (1.0f / (1.0f + expf(-(float)ov[1]))));
  res[2] = f2h((v2 - mu) * rs * g.z * (1.0f / (1.0f + expf(-(float)ov[2]))));
  res[3] = f2h((v3 - mu) * rs * g.w * (1.0f / (1.0f + expf(-(float)ov[3]))));
  *(f16x4*)(u + (long)tok * EMB + h * DH_ + lane * 4) = res;
}

// ---------------------------------------------------------------------------
extern "C" void kernel_launch(void* const* d_in, const int* in_sizes, int n_in,
                              void* d_out, int out_size, void* d_ws, size_t ws_size,
                              hipStream_t stream)
{
  (void)in_sizes; (void)n_in; (void)out_size; (void)ws_size;
  const float* x     = (const float*)d_in[0];
  const float* Wq    = (const float*)d_in[1];
  const float* Wk    = (const float*)d_in[2];
  const float* Wv    = (const float*)d_in[3];
  const float* Wog   = (const float*)d_in[4];
  const float* Wi    = (const float*)d_in[5];
  const float* bi    = (const float*)d_in[6];
  const float* Wf    = (const float*)d_in[7];
  const float* bfg   = (const float*)d_in[8];
  const float* gamma = (const float*)d_in[9];
  const float* Wout  = (const float*)d_in[10];

  char* base = (char*)d_ws;
  size_t off = 0;
  auto take = [&](size_t bytes) -> char* {
    char* p = base + off;
    off += (bytes + 255) & ~(size_t)255;
    return p;
  };
  _Float16* xh    = (_Float16*)take((size_t)TOKENS * EMB * 2);        //  8 MB
  _Float16* WcatT = (_Float16*)take((size_t)NQKVO * EMB * 2);         // 19 MB
  _Float16* WoutT = (_Float16*)take((size_t)EMB * EMB * 2);           //  8 MB
  _Float16* qkvo  = (_Float16*)take((size_t)TOKENS * NQKVO * 2);      // 19 MB
  _Float16* vt    = (_Float16*)take((size_t)2 * DH_ * S_LEN * 2);     //  1 MB
  _Float16* hb    = (_Float16*)take((size_t)NBH * S_LEN * DH_ * 2);   //  8 MB
  float*    ip    = (float*)take((size_t)NBH * S_LEN * 4);
  float*    fp    = (float*)take((size_t)NBH * S_LEN * 4);
  float*    aA    = (float*)take((size_t)NBH * S_LEN * 4);
  float*    mA    = (float*)take((size_t)NBH * S_LEN * 4);
  float*    vM    = (float*)take((size_t)NBH * S_LEN * 4);
  _Float16* ub    = xh;   // xh dead after QKVO GEMM
  float*    y     = (float*)d_out;

  const dim3 blk(256);
  // --- one-time casts / transposes ---
  cast_f16_kernel<<<dim3((TOKENS * EMB) / (256 * 8)), blk, 0, stream>>>(x, xh, (long)TOKENS * EMB);
  transpose_cast_kernel<float><<<dim3(32, 32), blk, 0, stream>>>(Wq,   EMB, WcatT,                     EMB, 0L, 0L);
  transpose_cast_kernel<float><<<dim3( 4, 32), blk, 0, stream>>>(Wk,   DH_, WcatT + (long)2048 * EMB,  EMB, 0L, 0L);
  transpose_cast_kernel<float><<<dim3( 4, 32), blk, 0, stream>>>(Wv,   DH_, WcatT + (long)2304 * EMB,  EMB, 0L, 0L);
  transpose_cast_kernel<float><<<dim3(32, 32), blk, 0, stream>>>(Wog,  EMB, WcatT + (long)2560 * EMB,  EMB, 0L, 0L);
  transpose_cast_kernel<float><<<dim3(32, 32), blk, 0, stream>>>(Wout, EMB, WoutT,                     EMB, 0L, 0L);
  // --- fused QKVO projection: [2048,4608] = xh @ WcatT^T ---
  gemm_bt_kernel<_Float16><<<dim3(NQKVO / 128, TOKENS / 128, 1), blk, 0, stream>>>(
      xh, WcatT, qkvo, EMB, EMB, EMB, NQKVO, 0L, 0L, 0L, 1, 0);
  // --- V^T per batch ---
  transpose_cast_kernel<_Float16><<<dim3(4, 16, 2), blk, 0, stream>>>(
      qkvo + 2304, NQKVO, vt, S_LEN, (long)S_LEN * NQKVO, (long)DH_ * S_LEN);
  // --- gates ---
  proj_if_kernel<<<dim3(TOKENS), blk, 0, stream>>>(x, Wi, bi, Wf, bfg, ip, fp);
  gates_kernel<<<dim3(NBH), dim3(1024), 0, stream>>>(fp, ip, aA, mA, vM);
  // --- fused mLSTM backend (triangle-paired, K/V direct-from-global) ---
  att_fused_kernel<<<dim3(16, NBH), blk, 0, stream>>>(qkvo, vt, aA, mA, vM, hb);
  // --- layernorm + output gate ---
  ln_gate_kernel<<<dim3(TOKENS * NH_ / 4), blk, 0, stream>>>(hb, qkvo, gamma, ub);
  // --- output projection ---
  gemm_bt_kernel<float><<<dim3(EMB / 128, TOKENS / 128, 1), blk, 0, stream>>>(
      ub, WoutT, y, EMB, EMB, EMB, EMB, 0L, 0L, 0L, 1, 0);
}

// Round 6
// 208.737 us; speedup vs baseline: 3.8508x; 1.0091x over previous
//
#include <hip/hip_runtime.h>
#include <math.h>

#define S_LEN  1024
#define EMB    2048
#define NH_    8
#define DH_    256
#define TOKENS 2048   // B*S
#define NBH    16     // B*NH
#define NQKVO  4608   // 2048 q | 256 k | 256 v | 2048 o

typedef __attribute__((ext_vector_type(4))) float    f32x4;
typedef __attribute__((ext_vector_type(8))) _Float16 f16x8;
typedef __attribute__((ext_vector_type(4))) _Float16 f16x4;

__device__ __forceinline__ _Float16 f2h(float f) { return (_Float16)f; }

// async global->LDS, 16B per lane; LDS dest = wave-uniform base + lane*16
__device__ __forceinline__ void gload16(const void* g, void* l) {
  __builtin_amdgcn_global_load_lds(
      (const __attribute__((address_space(1))) void*)g,
      (__attribute__((address_space(3))) void*)l, 16, 0, 0);
}

// ---------------------------------------------------------------------------
// f32->f16 cast, 8 elems/thread
// ---------------------------------------------------------------------------
__global__ __launch_bounds__(256) void cast_f16_kernel(
    const float* __restrict__ in, _Float16* __restrict__ out, long n)
{
  const long i = ((long)blockIdx.x * 256 + threadIdx.x) * 8;
  if (i >= n) return;
  const float4 a = *(const float4*)(in + i);
  const float4 b = *(const float4*)(in + i + 4);
  f16x8 o = {f2h(a.x), f2h(a.y), f2h(a.z), f2h(a.w),
             f2h(b.x), f2h(b.y), f2h(b.z), f2h(b.w)};
  *(f16x8*)(out + i) = o;
}

// ---------------------------------------------------------------------------
// Tiled transpose + cast to f16: out[z*sOut + c*ldo + r] = in[z*sIn + r*ldi + c]
// ---------------------------------------------------------------------------
template<typename TIN>
__global__ __launch_bounds__(256) void transpose_cast_kernel(
    const TIN* __restrict__ in, long ldi, _Float16* __restrict__ out, long ldo,
    long sIn, long sOut)
{
  __shared__ float t[64][65];
  const int lx = threadIdx.x & 63, ly = threadIdx.x >> 6;
  const long r0 = (long)blockIdx.y * 64, c0 = (long)blockIdx.x * 64;
  const TIN* ip = in + (long)blockIdx.z * sIn;
  _Float16* op = out + (long)blockIdx.z * sOut;
  #pragma unroll
  for (int i = 0; i < 16; ++i)
    t[ly + i * 4][lx] = (float)ip[(r0 + ly + i * 4) * ldi + c0 + lx];
  __syncthreads();
  #pragma unroll
  for (int i = 0; i < 16; ++i)
    op[(c0 + ly + i * 4) * ldo + r0 + lx] = f2h(t[lx][ly + i * 4]);
}

// ---------------------------------------------------------------------------
// f16 GEMM, both operands K-contiguous: C[M,N] = A[M,K] @ Bt[N,K]^T.
// 128x128 tile, BK=32, 4 waves (2x2). 3-deep prefetch pipeline with counted
// vmcnt(8)/4/0; LDS tiles XOR-swizzled (chunk ^= (row>>1)&3, source+read
// matched involution) -> ~2-way residual bank aliasing.  Flat grid with
// bijective XCD swizzle; B-panel (n) clustered per XCD.  CT = f16 or f32.
// ---------------------------------------------------------------------------
template<typename CT>
__global__ __launch_bounds__(256) void gemm_bt_kernel(
    const _Float16* __restrict__ Ag, const _Float16* __restrict__ Btg,
    CT* __restrict__ Cg, int K, int lda, int ldb, int ldc,
    long sA, long sB, long sC, int zdivB, int mtiles, int causal)
{
  __shared__ _Float16 As[3][128 * 32];
  __shared__ _Float16 Bs[3][128 * 32];
  const int tid = threadIdx.x;
  const int lane = tid & 63, wid = tid >> 6;
  // XCD-bijective swizzle (gridDim.x % 8 == 0): cluster n-panels per XCD
  const int cpx = gridDim.x >> 3;
  const int wg = ((int)blockIdx.x & 7) * cpx + ((int)blockIdx.x >> 3);
  const int m0 = (wg % mtiles) * 128;
  const int n0 = (wg / mtiles) * 128;
  const int z  = blockIdx.z;
  const _Float16* Ap = Ag + (long)z * sA + (long)m0 * lda;
  const _Float16* Bp = Btg + (long)(z / zdivB) * sB + (long)n0 * ldb;
  const int wr = wid >> 1, wc = wid & 1;
  const int lrow = lane & 15, kseg = lane >> 4;
  const int kl = causal ? ((m0 + 128 < K) ? m0 + 128 : K) : K;

  auto stage = [&](int b, int k0) {
    #pragma unroll
    for (int i = 0; i < 2; ++i) {
      const int cbase = (i * 4 + wid) * 64;            // wave-uniform chunk base
      const int row = (cbase >> 2) + (lane >> 2);      // 4 chunks per 32-wide row
      const int src = ((lane & 3) ^ ((row >> 1) & 3)) * 8;   // inverse-swizzled source
      gload16(Ap + (long)row * lda + k0 + src, (char*)As[b] + cbase * 16);
      gload16(Bp + (long)row * ldb + k0 + src, (char*)Bs[b] + cbase * 16);
    }
  };

  const int nt = kl >> 5;                              // K-tiles of 32
  f32x4 acc[4][4] = {};
  stage(0, 0);
  if (nt > 1) stage(1, 32);
  for (int t = 0; t < nt; ++t) {
    if (t + 2 < nt) {
      stage((t + 2) % 3, (t + 2) * 32);
      asm volatile("s_waitcnt vmcnt(8)" ::: "memory"); // t's 4+4 loads done; 8 in flight
    } else if (t + 1 < nt) {
      asm volatile("s_waitcnt vmcnt(4)" ::: "memory");
    } else {
      asm volatile("s_waitcnt vmcnt(0)" ::: "memory");
    }
    __builtin_amdgcn_s_barrier();
    __builtin_amdgcn_sched_barrier(0);
    const int buf = t % 3;
    f16x8 fa[4], fb[4];
    #pragma unroll
    for (int m = 0; m < 4; ++m) {
      const int row = wr * 64 + m * 16 + lrow;
      fa[m] = *(const f16x8*)&As[buf][row * 32 + ((kseg ^ ((row >> 1) & 3)) << 3)];
    }
    #pragma unroll
    for (int n = 0; n < 4; ++n) {
      const int row = wc * 64 + n * 16 + lrow;
      fb[n] = *(const f16x8*)&Bs[buf][row * 32 + ((kseg ^ ((row >> 1) & 3)) << 3)];
    }
    #pragma unroll
    for (int m = 0; m < 4; ++m)
      #pragma unroll
      for (int n = 0; n < 4; ++n)
        acc[m][n] = __builtin_amdgcn_mfma_f32_16x16x32_f16(fa[m], fb[n], acc[m][n], 0, 0, 0);
    __builtin_amdgcn_s_barrier();                      // reads done before overwrite
  }
  CT* Cp = Cg + (long)z * sC;
  #pragma unroll
  for (int m = 0; m < 4; ++m)
    #pragma unroll
    for (int n = 0; n < 4; ++n)
      #pragma unroll
      for (int i = 0; i < 4; ++i) {
        const int r = m0 + wr * 64 + m * 16 + kseg * 4 + i;  // row=(lane>>4)*4+i (m89)
        const int c = n0 + wc * 64 + n * 16 + lrow;          // col=lane&15
        Cp[(long)r * ldc + c] = (CT)acc[m][n][i];
      }
}

// ---------------------------------------------------------------------------
// i/f gate projections: per token, 16 dot products over E=2048, soft-capped.
// ---------------------------------------------------------------------------
__global__ __launch_bounds__(256) void proj_if_kernel(
    const float* __restrict__ x, const float* __restrict__ Wi, const float* __restrict__ bi,
    const float* __restrict__ Wf, const float* __restrict__ bfg,
    float* __restrict__ ip, float* __restrict__ fp)
{
  const int tok = blockIdx.x;
  const int tid = threadIdx.x;
  const float* xr = x + (long)tok * EMB;
  float ai[8] = {}, af[8] = {};
  #pragma unroll
  for (int j = 0; j < 8; ++j) {
    const int e = tid + j * 256;
    const float xe = xr[e];
    const float4* wi4 = (const float4*)(Wi + (long)e * 8);
    const float4* wf4 = (const float4*)(Wf + (long)e * 8);
    const float4 a0 = wi4[0], a1 = wi4[1], b0 = wf4[0], b1 = wf4[1];
    ai[0] += xe * a0.x; ai[1] += xe * a0.y; ai[2] += xe * a0.z; ai[3] += xe * a0.w;
    ai[4] += xe * a1.x; ai[5] += xe * a1.y; ai[6] += xe * a1.z; ai[7] += xe * a1.w;
    af[0] += xe * b0.x; af[1] += xe * b0.y; af[2] += xe * b0.z; af[3] += xe * b0.w;
    af[4] += xe * b1.x; af[5] += xe * b1.y; af[6] += xe * b1.z; af[7] += xe * b1.w;
  }
  #pragma unroll
  for (int hh = 0; hh < 8; ++hh)
    for (int off = 32; off; off >>= 1) {
      ai[hh] += __shfl_xor(ai[hh], off);
      af[hh] += __shfl_xor(af[hh], off);
    }
  __shared__ float red[4][16];
  const int lane = tid & 63, wid = tid >> 6;
  if (lane == 0) {
    #pragma unroll
    for (int hh = 0; hh < 8; ++hh) { red[wid][hh] = ai[hh]; red[wid][hh + 8] = af[hh]; }
  }
  __syncthreads();
  if (tid < 16) {
    const float v = red[0][tid] + red[1][tid] + red[2][tid] + red[3][tid];
    const int b = tok >> 10, s = tok & 1023;
    if (tid < 8) {
      const float zv = v + bi[tid];
      ip[(long)(b * NH_ + tid) * S_LEN + s] = 15.0f * tanhf(zv * (1.0f / 15.0f));
    } else {
      const int hh = tid - 8;
      const float zv = v + bfg[hh];
      fp[(long)(b * NH_ + hh) * S_LEN + s] = 15.0f * tanhf(zv * (1.0f / 15.0f));
    }
  }
}

// ---------------------------------------------------------------------------
// Per (b,h): logsigmoid, cumsum cf, a = i_pre - cf, running max m, vecM = cf+m.
// ---------------------------------------------------------------------------
__global__ __launch_bounds__(1024) void gates_kernel(
    const float* __restrict__ fp, const float* __restrict__ ip,
    float* __restrict__ aArr, float* __restrict__ mArr, float* __restrict__ vMArr)
{
  const int bh = blockIdx.x;
  const int s = threadIdx.x;
  __shared__ float sh[1024];
  const float f = fp[(long)bh * S_LEN + s];
  const float lsg = fminf(f, 0.0f) - log1pf(expf(-fabsf(f)));  // log_sigmoid
  float v = lsg;
  sh[s] = v; __syncthreads();
  for (int off = 1; off < 1024; off <<= 1) {
    const float o = (s >= off) ? sh[s - off] : 0.0f;
    __syncthreads();
    v += o; sh[s] = v;
    __syncthreads();
  }
  const float cf = v;
  const float a = ip[(long)bh * S_LEN + s] - cf;
  v = a;
  sh[s] = v; __syncthreads();
  for (int off = 1; off < 1024; off <<= 1) {
    const float o = (s >= off) ? sh[s - off] : -3.0e38f;
    __syncthreads();
    v = fmaxf(v, o); sh[s] = v;
    __syncthreads();
  }
  aArr[(long)bh * S_LEN + s] = a;
  mArr[(long)bh * S_LEN + s] = v;
  vMArr[(long)bh * S_LEN + s] = cf + v;
}

// ---------------------------------------------------------------------------
// Fused mLSTM attention, triangle-paired for causal load balance.
// Block (i, bh) owns q-subtiles qi=i and qi=31-i (32 rows each) => every
// block does exactly 9 subtile-passes.
// ---------------------------------------------------------------------------
__global__ __launch_bounds__(256) void att_fused_kernel(
    const _Float16* __restrict__ qkvo, const _Float16* __restrict__ vt,
    const float* __restrict__ aArr, const float* __restrict__ mArr,
    const float* __restrict__ vMArr, _Float16* __restrict__ hb)
{
  __shared__ _Float16 Qs[2][32 * 256];   // swizzled: 32 chunks/row, ^(row&7)
  __shared__ _Float16 Ws[2][32 * 128];   // swizzled: 16 chunks/row, ^((row&7)<<1)
  __shared__ float nsh[2][4][32];
  __shared__ float invs[2][32];
  const int tid = threadIdx.x;
  const int lane = tid & 63, wid = tid >> 6;
  const int bh = blockIdx.y;
  const int b = bh >> 3, h = bh & 7;
  const int r0[2] = { (int)blockIdx.x * 32, (31 - (int)blockIdx.x) * 32 };
  const _Float16* Qg = qkvo + (long)(b * S_LEN) * NQKVO + h * DH_;
  const _Float16* Kg = qkvo + (long)(b * S_LEN) * NQKVO + 2048;
  const _Float16* Vt = vt + (long)b * DH_ * S_LEN;
  const float* aA = aArr + (long)bh * S_LEN;
  const float* mA = mArr + (long)bh * S_LEN;
  const int lrow = lane & 15, kseg = lane >> 4;
  const int tbase = 32 * wid;

  #pragma unroll
  for (int i = 0; i < 8; ++i) {
    const int cbase = (i * 4 + wid) * 64;   // wave-uniform; sub uniform per iter
    const int c = cbase + lane;
    const int sub = c >> 10, row = (c >> 5) & 31, slot = c & 31;
    gload16(Qg + (long)(r0[sub] + row) * NQKVO + (slot ^ (row & 7)) * 8,
            (char*)Qs + cbase * 16);
  }

  float m_s[2][2][4];
  #pragma unroll
  for (int sub = 0; sub < 2; ++sub)
    #pragma unroll
    for (int m = 0; m < 2; ++m)
      #pragma unroll
      for (int i = 0; i < 4; ++i)
        m_s[sub][m][i] = mA[r0[sub] + m * 16 + kseg * 4 + i];
  __syncthreads();   // Q staged (drains vmcnt)

  f32x4 hacc[2][2][4] = {};
  float nacc[2][2][4] = {};
  for (int n0 = 0; n0 <= r0[1]; n0 += 128) {
    // ---- QK^T: K frags global->reg, shared across subtiles ----
    f32x4 acc[2][2][2] = {};
    for (int k0 = 0; k0 < DH_; k0 += 32) {
      f16x8 fb[2];
      #pragma unroll
      for (int n = 0; n < 2; ++n)
        fb[n] = *(const f16x8*)(Kg + (long)(n0 + tbase + n * 16 + lrow) * NQKVO + k0 + kseg * 8);
      const int chunk = (k0 >> 3) + kseg;
      #pragma unroll
      for (int sub = 0; sub < 2; ++sub) {
        if (n0 > r0[sub]) continue;
        #pragma unroll
        for (int m = 0; m < 2; ++m) {
          const int qrow = m * 16 + lrow;
          const f16x8 fa = *(const f16x8*)&Qs[sub][qrow * 256 + ((chunk ^ (qrow & 7)) << 3)];
          #pragma unroll
          for (int n = 0; n < 2; ++n)
            acc[sub][m][n] = __builtin_amdgcn_mfma_f32_16x16x32_f16(fa, fb[n], acc[sub][m][n], 0, 0, 0);
        }
      }
    }
    // ---- weighting -> Ws (swizzled), row-sum accumulation ----
    float a_t[2];
    #pragma unroll
    for (int n = 0; n < 2; ++n) a_t[n] = aA[n0 + tbase + n * 16 + lrow];
    #pragma unroll
    for (int sub = 0; sub < 2; ++sub) {
      if (n0 > r0[sub]) continue;
      #pragma unroll
      for (int m = 0; m < 2; ++m)
        #pragma unroll
        for (int n = 0; n < 2; ++n)
          #pragma unroll
          for (int i = 0; i < 4; ++i) {
            const int sr = m * 16 + kseg * 4 + i;       // local row 0..31
            const int t  = tbase + n * 16 + lrow;       // local col 0..127
            float w = 0.0f;
            if (n0 + t <= r0[sub] + sr)
              w = acc[sub][m][n][i] * 0.0625f * expf(a_t[n] - m_s[sub][m][i]);
            nacc[sub][m][i] += w;
            Ws[sub][sr * 128 + (((t >> 3) ^ ((sr & 7) << 1)) << 3) + (t & 7)] = f2h(w);
          }
    }
    __syncthreads();
    // ---- PV: V frags global->reg (shared), Ws from LDS ----
    for (int kt = 0; kt < 128; kt += 32) {
      f16x8 vb[4];
      #pragma unroll
      for (int n = 0; n < 4; ++n)
        vb[n] = *(const f16x8*)(Vt + (long)(64 * wid + n * 16 + lrow) * S_LEN + n0 + kt + kseg * 8);
      const int chunk = (kt >> 3) + kseg;
      #pragma unroll
      for (int sub = 0; sub < 2; ++sub) {
        if (n0 > r0[sub]) continue;
        #pragma unroll
        for (int m = 0; m < 2; ++m) {
          const int row = m * 16 + lrow;
          const f16x8 wa = *(const f16x8*)&Ws[sub][row * 128 + ((chunk ^ ((row & 7) << 1)) << 3)];
          #pragma unroll
          for (int n = 0; n < 4; ++n)
            hacc[sub][m][n] = __builtin_amdgcn_mfma_f32_16x16x32_f16(wa, vb[n], hacc[sub][m][n], 0, 0, 0);
        }
      }
    }
    __syncthreads();   // Ws reads done before next pass overwrites
  }
  // ---- row sums -> invn ----
  #pragma unroll
  for (int sub = 0; sub < 2; ++sub)
    #pragma unroll
    for (int m = 0; m < 2; ++m)
      #pragma unroll
      for (int i = 0; i < 4; ++i) {
        float v = nacc[sub][m][i];
        v += __shfl_xor(v, 1); v += __shfl_xor(v, 2);
        v += __shfl_xor(v, 4); v += __shfl_xor(v, 8);
        if (lrow == 0) nsh[sub][wid][m * 16 + kseg * 4 + i] = v;
      }
  __syncthreads();
  if (tid < 64) {
    const int sub = tid >> 5, sr = tid & 31;
    const float tot = nsh[sub][0][sr] + nsh[sub][1][sr] + nsh[sub][2][sr] + nsh[sub][3][sr];
    const float vm = vMArr[(long)bh * S_LEN + r0[sub] + sr];
    const float vecN = fmaxf(fabsf(tot), expf(-vm));
    invs[sub][sr] = 1.0f / (vecN + 1e-6f);
  }
  __syncthreads();
  #pragma unroll
  for (int sub = 0; sub < 2; ++sub)
    #pragma unroll
    for (int m = 0; m < 2; ++m)
      #pragma unroll
      for (int n = 0; n < 4; ++n)
        #pragma unroll
        for (int i = 0; i < 4; ++i) {
          const int row = m * 16 + kseg * 4 + i;
          const int d = 64 * wid + n * 16 + lrow;
          hb[((long)bh * S_LEN + r0[sub] + row) * DH_ + d] = f2h(hacc[sub][m][n][i] * invs[sub][row]);
        }
}

// ---------------------------------------------------------------------------
// One wave per (token, head) row: LN over DH=256 (f32), *gamma, *sigmoid(o).
// ---------------------------------------------------------------------------
__global__ __launch_bounds__(256) void ln_gate_kernel(
    const _Float16* __restrict__ hbuf,
    const _Float16* __restrict__ qkvo, const float* __restrict__ gamma,
    _Float16* __restrict__ u)
{
  const int wid = threadIdx.x >> 6, lane = threadIdx.x & 63;
  const int row = blockIdx.x * 4 + wid;   // row = tok*8 + h
  const int tok = row >> 3, h = row & 7;
  const int b = tok >> 10, s = tok & 1023;
  const int bh = b * NH_ + h;
  const f16x4 hv = *(const f16x4*)(hbuf + ((long)bh * S_LEN + s) * DH_ + lane * 4);
  const float v0 = (float)hv[0], v1 = (float)hv[1], v2 = (float)hv[2], v3 = (float)hv[3];
  float s1 = v0 + v1 + v2 + v3;
  float s2 = v0 * v0 + v1 * v1 + v2 * v2 + v3 * v3;
  for (int off = 32; off; off >>= 1) { s1 += __shfl_xor(s1, off); s2 += __shfl_xor(s2, off); }
  const float mu = s1 * (1.0f / 256.0f);
  const float var = s2 * (1.0f / 256.0f) - mu * mu;
  const float rs = rsqrtf(var + 1e-6f);
  const float4 g = *(const float4*)(gamma + h * DH_ + lane * 4);
  const f16x4 ov = *(const f16x4*)(qkvo + (long)tok * NQKVO + 2560 + h * DH_ + lane * 4);
  f16x4 res;
  res[0] = f2h((v0 - mu) * rs * g.x * (1.0f / (1.0f + expf(-(float)ov[0]))));
  res[1] = f2h((v1 - mu) * rs * g.y * (1.0f / (1.0f + expf(-(float)ov[1]))));
  res[2] = f2h((v2 - mu) * rs * g.z * (1.0f / (1.0f + expf(-(float)ov[2]))));
  res[3] = f2h((v3 - mu) * rs * g.w * (1.0f / (1.0f + expf(-(float)ov[3]))));
  *(f16x4*)(u + (long)tok * EMB + h * DH_ + lane * 4) = res;
}

// ---------------------------------------------------------------------------
extern "C" void kernel_launch(void* const* d_in, const int* in_sizes, int n_in,
                              void* d_out, int out_size, void* d_ws, size_t ws_size,
                              hipStream_t stream)
{
  (void)in_sizes; (void)n_in; (void)out_size; (void)ws_size;
  const float* x     = (const float*)d_in[0];
  const float* Wq    = (const float*)d_in[1];
  const float* Wk    = (const float*)d_in[2];
  const float* Wv    = (const float*)d_in[3];
  const float* Wog   = (const float*)d_in[4];
  const float* Wi    = (const float*)d_in[5];
  const float* bi    = (const float*)d_in[6];
  const float* Wf    = (const float*)d_in[7];
  const float* bfg   = (const float*)d_in[8];
  const float* gamma = (const float*)d_in[9];
  const float* Wout  = (const float*)d_in[10];

  char* base = (char*)d_ws;
  size_t off = 0;
  auto take = [&](size_t bytes) -> char* {
    char* p = base + off;
    off += (bytes + 255) & ~(size_t)255;
    return p;
  };
  _Float16* xh    = (_Float16*)take((size_t)TOKENS * EMB * 2);        //  8 MB
  _Float16* WcatT = (_Float16*)take((size_t)NQKVO * EMB * 2);         // 19 MB
  _Float16* WoutT = (_Float16*)take((size_t)EMB * EMB * 2);           //  8 MB
  _Float16* qkvo  = (_Float16*)take((size_t)TOKENS * NQKVO * 2);      // 19 MB
  _Float16* vt    = (_Float16*)take((size_t)2 * DH_ * S_LEN * 2);     //  1 MB
  _Float16* hb    = (_Float16*)take((size_t)NBH * S_LEN * DH_ * 2);   //  8 MB
  float*    ip    = (float*)take((size_t)NBH * S_LEN * 4);
  float*    fp    = (float*)take((size_t)NBH * S_LEN * 4);
  float*    aA    = (float*)take((size_t)NBH * S_LEN * 4);
  float*    mA    = (float*)take((size_t)NBH * S_LEN * 4);
  float*    vM    = (float*)take((size_t)NBH * S_LEN * 4);
  _Float16* ub    = xh;   // xh dead after QKVO GEMM
  float*    y     = (float*)d_out;

  const dim3 blk(256);
  // --- one-time casts / transposes ---
  cast_f16_kernel<<<dim3((TOKENS * EMB) / (256 * 8)), blk, 0, stream>>>(x, xh, (long)TOKENS * EMB);
  transpose_cast_kernel<float><<<dim3(32, 32), blk, 0, stream>>>(Wq,   EMB, WcatT,                     EMB, 0L, 0L);
  transpose_cast_kernel<float><<<dim3( 4, 32), blk, 0, stream>>>(Wk,   DH_, WcatT + (long)2048 * EMB,  EMB, 0L, 0L);
  transpose_cast_kernel<float><<<dim3( 4, 32), blk, 0, stream>>>(Wv,   DH_, WcatT + (long)2304 * EMB,  EMB, 0L, 0L);
  transpose_cast_kernel<float><<<dim3(32, 32), blk, 0, stream>>>(Wog,  EMB, WcatT + (long)2560 * EMB,  EMB, 0L, 0L);
  transpose_cast_kernel<float><<<dim3(32, 32), blk, 0, stream>>>(Wout, EMB, WoutT,                     EMB, 0L, 0L);
  // --- fused QKVO projection: [2048,4608] = xh @ WcatT^T (36 n-tiles x 16 m-tiles) ---
  gemm_bt_kernel<_Float16><<<dim3(36 * 16), blk, 0, stream>>>(
      xh, WcatT, qkvo, EMB, EMB, EMB, NQKVO, 0L, 0L, 0L, 1, 16, 0);
  // --- V^T per batch ---
  transpose_cast_kernel<_Float16><<<dim3(4, 16, 2), blk, 0, stream>>>(
      qkvo + 2304, NQKVO, vt, S_LEN, (long)S_LEN * NQKVO, (long)DH_ * S_LEN);
  // --- gates ---
  proj_if_kernel<<<dim3(TOKENS), blk, 0, stream>>>(x, Wi, bi, Wf, bfg, ip, fp);
  gates_kernel<<<dim3(NBH), dim3(1024), 0, stream>>>(fp, ip, aA, mA, vM);
  // --- fused mLSTM backend (triangle-paired, K/V direct-from-global) ---
  att_fused_kernel<<<dim3(16, NBH), blk, 0, stream>>>(qkvo, vt, aA, mA, vM, hb);
  // --- layernorm + output gate ---
  ln_gate_kernel<<<dim3(TOKENS * NH_ / 4), blk, 0, stream>>>(hb, qkvo, gamma, ub);
  // --- output projection (16 n-tiles x 16 m-tiles) ---
  gemm_bt_kernel<float><<<dim3(16 * 16), blk, 0, stream>>>(
      ub, WoutT, y, EMB, EMB, EMB, EMB, 0L, 0L, 0L, 1, 16, 0);
}